// Round 4
// baseline (2149.957 us; speedup 1.0000x reference)
//
#include <hip/hip_runtime.h>

#define NA 100000
#define NB 100000
#define ND 50000
#define HDIM 128
#define DOUT 16
// concatenated dst-node space: rel0 d:[0,ND) rel1 d:[ND,2ND) rel2 a:[2ND,2ND+NA) rel3 b:[2ND+NA,...)
#define NODE_TOT (2*ND + NA + NB)

// ---------------- weights: W_r = coef[r,0]*basis[0] + coef[r,1]*basis[1] ----------------
__global__ __launch_bounds__(256) void k_weights(const float* __restrict__ basis,
                                                 const float* __restrict__ coef,
                                                 float* __restrict__ W0, float* __restrict__ W1,
                                                 int r0, int r1, int n) {
    int i = blockIdx.x * 256 + threadIdx.x;
    if (i >= n) return;
    float b0 = basis[i], b1 = basis[n + i];
    W0[i] = coef[r0*2+0]*b0 + coef[r0*2+1]*b1;
    W1[i] = coef[r1*2+0]*b0 + coef[r1*2+1]*b1;
}

// ---------------- batched CSR build over all 4 relations ----------------
__global__ __launch_bounds__(256) void k_degree4(const int* __restrict__ d0, const int* __restrict__ d1,
                                                 const int* __restrict__ d2, const int* __restrict__ d3,
                                                 int E0, int E1, int E2, int E3,
                                                 int* __restrict__ deg) {
    int g = blockIdx.x * 256 + threadIdx.x;
    int node;
    if (g < E0)                node = d0[g];
    else if (g < E0+E1)        node = ND + d1[g-E0];
    else if (g < E0+E1+E2)     node = 2*ND + d2[g-E0-E1];
    else if (g < E0+E1+E2+E3)  node = 2*ND+NA + d3[g-E0-E1-E2];
    else return;
    atomicAdd(&deg[node], 1);
}

__global__ __launch_bounds__(1024) void k_scan1(const int* __restrict__ deg,
                                                int* __restrict__ offs,
                                                int* __restrict__ bsum, int N) {
    __shared__ int sh[1024];
    int i = blockIdx.x * 1024 + threadIdx.x;
    int v = (i < N) ? deg[i] : 0;
    sh[threadIdx.x] = v;
    __syncthreads();
    for (int off = 1; off < 1024; off <<= 1) {
        int t = (threadIdx.x >= off) ? sh[threadIdx.x - off] : 0;
        __syncthreads();
        sh[threadIdx.x] += t;
        __syncthreads();
    }
    if (i < N) offs[i + 1] = sh[threadIdx.x];
    if (threadIdx.x == 1023) bsum[blockIdx.x] = sh[1023];
    if (i == 0) offs[0] = 0;
}

__global__ __launch_bounds__(1024) void k_scan2(int* __restrict__ bsum, int nb) {
    __shared__ int sh[1024];
    int t = threadIdx.x;
    sh[t] = (t < nb) ? bsum[t] : 0;
    __syncthreads();
    for (int off = 1; off < 1024; off <<= 1) {
        int v = (t >= off) ? sh[t - off] : 0;
        __syncthreads();
        sh[t] += v;
        __syncthreads();
    }
    if (t < nb) bsum[t] = sh[t];
}

__global__ __launch_bounds__(1024) void k_scan3(int* __restrict__ offs,
                                                const int* __restrict__ bsum, int N) {
    int i = blockIdx.x * 1024 + threadIdx.x;
    if (blockIdx.x > 0 && i < N) offs[i + 1] += bsum[blockIdx.x - 1];
}

__global__ __launch_bounds__(256) void k_copy_i(const int* __restrict__ a,
                                                int* __restrict__ b, int N) {
    int i = blockIdx.x * 256 + threadIdx.x;
    if (i < N) b[i] = a[i];
}

__global__ __launch_bounds__(256) void k_fill4(const int* __restrict__ s0p, const int* __restrict__ d0p,
                                               const int* __restrict__ s1p, const int* __restrict__ d1p,
                                               const int* __restrict__ s2p, const int* __restrict__ d2p,
                                               const int* __restrict__ s3p, const int* __restrict__ d3p,
                                               int E0, int E1, int E2, int E3,
                                               int* __restrict__ cursor, int* __restrict__ csr) {
    int g = blockIdx.x * 256 + threadIdx.x;
    int node, src;
    if (g < E0)                { node = d0p[g];                    src = s0p[g]; }
    else if (g < E0+E1)        { node = ND + d1p[g-E0];            src = s1p[g-E0]; }
    else if (g < E0+E1+E2)     { node = 2*ND + d2p[g-E0-E1];       src = s2p[g-E0-E1]; }
    else if (g < E0+E1+E2+E3)  { node = 2*ND+NA + d3p[g-E0-E1-E2]; src = s3p[g-E0-E1-E2]; }
    else return;
    int p = atomicAdd(&cursor[node], 1);
    csr[p] = src;
}

// ---------------- gather (CSR, mean-normalized, optional bias+relu) ----------------
__global__ __launch_bounds__(256) void k_gather128(const float* __restrict__ feat,
                                                   const int* __restrict__ offs,
                                                   const int* __restrict__ csr,
                                                   const float* __restrict__ bias, int relu,
                                                   float* __restrict__ out, int nrows) {
    int w = threadIdx.x >> 6;
    int lane = threadIdx.x & 63;
    int row = blockIdx.x * 4 + w;
    if (row >= nrows) return;
    int s0 = offs[row], s1 = offs[row + 1];
    float2 acc = make_float2(0.f, 0.f);
    int j = s0;
    for (; j + 1 < s1; j += 2) {
        int sA = csr[j], sB = csr[j + 1];
        const float2 a = *reinterpret_cast<const float2*>(feat + (size_t)sA*HDIM + lane*2);
        const float2 b = *reinterpret_cast<const float2*>(feat + (size_t)sB*HDIM + lane*2);
        acc.x += a.x + b.x; acc.y += a.y + b.y;
    }
    if (j < s1) {
        int sA = csr[j];
        const float2 a = *reinterpret_cast<const float2*>(feat + (size_t)sA*HDIM + lane*2);
        acc.x += a.x; acc.y += a.y;
    }
    float sc = 1.0f / fmaxf((float)(s1 - s0), 1.0f);
    float vx = acc.x * sc, vy = acc.y * sc;
    if (bias) {
        const float2 bi = *reinterpret_cast<const float2*>(bias + lane*2);
        vx += bi.x; vy += bi.y;
    }
    if (relu) { vx = fmaxf(vx, 0.f); vy = fmaxf(vy, 0.f); }
    *reinterpret_cast<float2*>(out + (size_t)row*HDIM + lane*2) = make_float2(vx, vy);
}

// ---------------- LDS-tiled GEMM, 64x128 tile, 4x8 acc/thread ----------------
// A staged transposed As[k][row] pitch 68; W staged Ws[k][col] pitch 132.
// A global load: row=t>>2, k=(t&3)*4 -> 64B-contiguous per 4 lanes.
__global__ __launch_bounds__(256, 4) void k_gemm1_64(const float* __restrict__ A,
                                                     const float* __restrict__ W,
                                                     const float* __restrict__ bias, int relu,
                                                     float* __restrict__ out, int nrows) {
    __shared__ float As[16 * 68];
    __shared__ float Ws[16 * 132];
    const int t = threadIdx.x;
    const int tx = t & 15, ty = t >> 4;
    const int row0 = blockIdx.x * 64;
    const int ar = t >> 2, ak = (t & 3) * 4;
    const int wk = t >> 4, wc = t & 15;
    float acc[4][8];
    #pragma unroll
    for (int i = 0; i < 4; ++i)
        #pragma unroll
        for (int j = 0; j < 8; ++j) acc[i][j] = 0.f;
    const bool arow_ok = (row0 + ar) < nrows;
    const float* Arow = A + (size_t)(row0 + ar) * HDIM;

    for (int k0 = 0; k0 < HDIM; k0 += 16) {
        float4 av = make_float4(0.f,0.f,0.f,0.f);
        if (arow_ok) av = *(const float4*)(Arow + k0 + ak);
        const float4 wv0 = *(const float4*)(W + (size_t)(k0 + wk)*HDIM + wc*4);
        const float4 wv1 = *(const float4*)(W + (size_t)(k0 + wk)*HDIM + 64 + wc*4);
        __syncthreads();
        As[(ak+0)*68 + ar] = av.x; As[(ak+1)*68 + ar] = av.y;
        As[(ak+2)*68 + ar] = av.z; As[(ak+3)*68 + ar] = av.w;
        *(float4*)(Ws + wk*132 + wc*4) = wv0;
        *(float4*)(Ws + wk*132 + 64 + wc*4) = wv1;
        __syncthreads();
        #pragma unroll
        for (int k = 0; k < 16; ++k) {
            const float4 a0 = *(const float4*)(As + k*68 + ty*4);
            const float4 w0 = *(const float4*)(Ws + k*132 + tx*4);
            const float4 w1 = *(const float4*)(Ws + k*132 + 64 + tx*4);
            const float a[4] = {a0.x,a0.y,a0.z,a0.w};
            const float w[8] = {w0.x,w0.y,w0.z,w0.w,w1.x,w1.y,w1.z,w1.w};
            #pragma unroll
            for (int i = 0; i < 4; ++i)
                #pragma unroll
                for (int j = 0; j < 8; ++j)
                    acc[i][j] += a[i]*w[j];
        }
    }
    float bj[8] = {0,0,0,0,0,0,0,0};
    if (bias) {
        const float4 b0 = *(const float4*)(bias + tx*4);
        const float4 b1 = *(const float4*)(bias + 64 + tx*4);
        bj[0]=b0.x; bj[1]=b0.y; bj[2]=b0.z; bj[3]=b0.w;
        bj[4]=b1.x; bj[5]=b1.y; bj[6]=b1.z; bj[7]=b1.w;
    }
    #pragma unroll
    for (int i = 0; i < 4; ++i) {
        int r = row0 + ty*4 + i;
        if (r >= nrows) continue;
        float o[8];
        #pragma unroll
        for (int j = 0; j < 8; ++j) {
            float v = acc[i][j] + bj[j];
            o[j] = relu ? fmaxf(v, 0.f) : v;
        }
        *(float4*)(out + (size_t)r*HDIM + tx*4)      = make_float4(o[0],o[1],o[2],o[3]);
        *(float4*)(out + (size_t)r*HDIM + 64 + tx*4) = make_float4(o[4],o[5],o[6],o[7]);
    }
}

__global__ __launch_bounds__(256, 4) void k_gemm2_64(const float* __restrict__ A, const float* __restrict__ B,
                                                     const float* __restrict__ WA, const float* __restrict__ WB,
                                                     const float* __restrict__ bias,
                                                     float* __restrict__ out, int nrows) {
    __shared__ float As[16 * 68];
    __shared__ float Bs[16 * 68];
    __shared__ float WAs[16 * 132];
    __shared__ float WBs[16 * 132];
    const int t = threadIdx.x;
    const int tx = t & 15, ty = t >> 4;
    const int row0 = blockIdx.x * 64;
    const int ar = t >> 2, ak = (t & 3) * 4;
    const int wk = t >> 4, wc = t & 15;
    float acc[4][8];
    #pragma unroll
    for (int i = 0; i < 4; ++i)
        #pragma unroll
        for (int j = 0; j < 8; ++j) acc[i][j] = 0.f;
    const bool arow_ok = (row0 + ar) < nrows;
    const float* Arow = A + (size_t)(row0 + ar) * HDIM;
    const float* Brow = B + (size_t)(row0 + ar) * HDIM;

    for (int k0 = 0; k0 < HDIM; k0 += 16) {
        float4 av = make_float4(0.f,0.f,0.f,0.f), bv = av;
        if (arow_ok) {
            av = *(const float4*)(Arow + k0 + ak);
            bv = *(const float4*)(Brow + k0 + ak);
        }
        const float4 wa0 = *(const float4*)(WA + (size_t)(k0 + wk)*HDIM + wc*4);
        const float4 wa1 = *(const float4*)(WA + (size_t)(k0 + wk)*HDIM + 64 + wc*4);
        const float4 wb0 = *(const float4*)(WB + (size_t)(k0 + wk)*HDIM + wc*4);
        const float4 wb1 = *(const float4*)(WB + (size_t)(k0 + wk)*HDIM + 64 + wc*4);
        __syncthreads();
        As[(ak+0)*68 + ar] = av.x; As[(ak+1)*68 + ar] = av.y;
        As[(ak+2)*68 + ar] = av.z; As[(ak+3)*68 + ar] = av.w;
        Bs[(ak+0)*68 + ar] = bv.x; Bs[(ak+1)*68 + ar] = bv.y;
        Bs[(ak+2)*68 + ar] = bv.z; Bs[(ak+3)*68 + ar] = bv.w;
        *(float4*)(WAs + wk*132 + wc*4) = wa0;
        *(float4*)(WAs + wk*132 + 64 + wc*4) = wa1;
        *(float4*)(WBs + wk*132 + wc*4) = wb0;
        *(float4*)(WBs + wk*132 + 64 + wc*4) = wb1;
        __syncthreads();
        #pragma unroll
        for (int k = 0; k < 16; ++k) {
            const float4 a0 = *(const float4*)(As + k*68 + ty*4);
            const float4 b0 = *(const float4*)(Bs + k*68 + ty*4);
            const float4 x0 = *(const float4*)(WAs + k*132 + tx*4);
            const float4 x1 = *(const float4*)(WAs + k*132 + 64 + tx*4);
            const float4 y0 = *(const float4*)(WBs + k*132 + tx*4);
            const float4 y1 = *(const float4*)(WBs + k*132 + 64 + tx*4);
            const float a[4]  = {a0.x,a0.y,a0.z,a0.w};
            const float b[4]  = {b0.x,b0.y,b0.z,b0.w};
            const float wa[8] = {x0.x,x0.y,x0.z,x0.w,x1.x,x1.y,x1.z,x1.w};
            const float wb[8] = {y0.x,y0.y,y0.z,y0.w,y1.x,y1.y,y1.z,y1.w};
            #pragma unroll
            for (int i = 0; i < 4; ++i)
                #pragma unroll
                for (int j = 0; j < 8; ++j)
                    acc[i][j] += a[i]*wa[j] + b[i]*wb[j];
        }
    }
    const float4 b0 = *(const float4*)(bias + tx*4);
    const float4 b1 = *(const float4*)(bias + 64 + tx*4);
    const float bj[8] = {b0.x,b0.y,b0.z,b0.w,b1.x,b1.y,b1.z,b1.w};
    #pragma unroll
    for (int i = 0; i < 4; ++i) {
        int r = row0 + ty*4 + i;
        if (r >= nrows) continue;
        float o[8];
        #pragma unroll
        for (int j = 0; j < 8; ++j) o[j] = fmaxf(acc[i][j] + bj[j], 0.f);
        *(float4*)(out + (size_t)r*HDIM + tx*4)      = make_float4(o[0],o[1],o[2],o[3]);
        *(float4*)(out + (size_t)r*HDIM + 64 + tx*4) = make_float4(o[4],o[5],o[6],o[7]);
    }
}

// transform h1 by W2 ([128,16], LDS-staged): one thread per row
__global__ __launch_bounds__(256) void k_trans16(const float* __restrict__ A,
                                                 const float* __restrict__ W,
                                                 float* __restrict__ out, int nrows) {
    __shared__ float Ws[HDIM * DOUT];
    const int t = threadIdx.x;
    *(float4*)(Ws + t*8)     = *(const float4*)(W + t*8);
    *(float4*)(Ws + t*8 + 4) = *(const float4*)(W + t*8 + 4);
    __syncthreads();
    int row = blockIdx.x * 256 + t;
    if (row >= nrows) return;
    const float* a = A + (size_t)row * HDIM;
    float acc[DOUT];
    #pragma unroll
    for (int j = 0; j < DOUT; ++j) acc[j] = 0.f;
    #pragma unroll 4
    for (int k = 0; k < HDIM; k += 4) {
        const float4 av = *(const float4*)(a + k);
        #pragma unroll
        for (int j = 0; j < DOUT; ++j)
            acc[j] += av.x*Ws[k*DOUT + j] + av.y*Ws[(k+1)*DOUT + j]
                    + av.z*Ws[(k+2)*DOUT + j] + av.w*Ws[(k+3)*DOUT + j];
    }
    #pragma unroll
    for (int j = 0; j < DOUT; j += 4)
        *(float4*)(out + (size_t)row*DOUT + j) = make_float4(acc[j],acc[j+1],acc[j+2],acc[j+3]);
}

// final: out[d] = mean-gather(t0 via rel0) + mean-gather(t1 via rel1) + bias
__global__ __launch_bounds__(256) void k_gather16_combine(const float* __restrict__ t0,
                                                          const float* __restrict__ t1,
                                                          const int* __restrict__ offs0,
                                                          const int* __restrict__ offs1,
                                                          const int* __restrict__ csr,
                                                          const float* __restrict__ bias,
                                                          float* __restrict__ out, int nrows) {
    int t = threadIdx.x;
    int row = blockIdx.x * 64 + (t >> 2);
    if (row >= nrows) return;
    int c = (t & 3) * 4;
    float4 acc = make_float4(0.f, 0.f, 0.f, 0.f);
    int s0 = offs0[row], s1 = offs0[row + 1];
    for (int j = s0; j < s1; ++j) {
        int s = csr[j];
        float4 v = *reinterpret_cast<const float4*>(t0 + (size_t)s*DOUT + c);
        acc.x += v.x; acc.y += v.y; acc.z += v.z; acc.w += v.w;
    }
    float sc = 1.0f / fmaxf((float)(s1 - s0), 1.0f);
    acc.x *= sc; acc.y *= sc; acc.z *= sc; acc.w *= sc;
    float4 acc2 = make_float4(0.f, 0.f, 0.f, 0.f);
    int u0 = offs1[row], u1 = offs1[row + 1];
    for (int j = u0; j < u1; ++j) {
        int s = csr[j];
        float4 v = *reinterpret_cast<const float4*>(t1 + (size_t)s*DOUT + c);
        acc2.x += v.x; acc2.y += v.y; acc2.z += v.z; acc2.w += v.w;
    }
    float sc2 = 1.0f / fmaxf((float)(u1 - u0), 1.0f);
    float4 bi = *reinterpret_cast<const float4*>(bias + c);
    acc.x += acc2.x*sc2 + bi.x; acc.y += acc2.y*sc2 + bi.y;
    acc.z += acc2.z*sc2 + bi.z; acc.w += acc2.w*sc2 + bi.w;
    *reinterpret_cast<float4*>(out + (size_t)row*DOUT + c) = acc;
}

extern "C" void kernel_launch(void* const* d_in, const int* in_sizes, int n_in,
                              void* d_out, int out_size, void* d_ws, size_t ws_size,
                              hipStream_t stream) {
    const float* feat_a = (const float*)d_in[0];
    const float* feat_b = (const float*)d_in[1];
    const float* basis0 = (const float*)d_in[3];
    const float* coef0  = (const float*)d_in[4];
    const float* bias0  = (const float*)d_in[5];
    const float* basis1 = (const float*)d_in[6];
    const float* coef1  = (const float*)d_in[7];
    const float* bias1  = (const float*)d_in[8];
    const float* basis2 = (const float*)d_in[9];
    const float* coef2  = (const float*)d_in[10];
    const float* bias2  = (const float*)d_in[11];
    const int* s0 = (const int*)d_in[12]; const int* d0 = (const int*)d_in[13];
    const int* s1 = (const int*)d_in[14]; const int* d1 = (const int*)d_in[15];
    const int* s2 = (const int*)d_in[16]; const int* d2 = (const int*)d_in[17];
    const int* s3 = (const int*)d_in[18]; const int* d3 = (const int*)d_in[19];
    const int E0 = in_sizes[12], E1 = in_sizes[14], E2 = in_sizes[16], E3 = in_sizes[18];
    const int Etot = E0 + E1 + E2 + E3;

    // ---- workspace carve-up ----
    char* base = (char*)d_ws;
    auto alloc = [&](size_t bytes) { char* p = base; base += (bytes + 255) & ~(size_t)255; return p; };
    float* W00 = (float*)alloc(HDIM*HDIM*4);
    float* W01 = (float*)alloc(HDIM*HDIM*4);
    float* W12 = (float*)alloc(HDIM*HDIM*4);
    float* W13 = (float*)alloc(HDIM*HDIM*4);
    float* W20 = (float*)alloc(HDIM*DOUT*4);
    float* W21 = (float*)alloc(HDIM*DOUT*4);
    int* offs_all = (int*)alloc((NODE_TOT + 1) * 4);
    int* csr_all  = (int*)alloc((size_t)Etot * 4);
    int* bsum     = (int*)alloc(2048 * 4);
    int* ideg     = (int*)alloc(NODE_TOT * 4);     // reused as cursor
    float* aggA = (float*)alloc((size_t)ND*HDIM*4);   // layer0 aggA -> t2 -> t1a/t1b
    float* aggB = (float*)alloc((size_t)ND*HDIM*4);   // layer0 aggB -> t3
    float* h0d  = (float*)alloc((size_t)ND*HDIM*4);
    float* h1a  = (float*)alloc((size_t)NA*HDIM*4);
    float* h1b  = (float*)alloc((size_t)NB*HDIM*4);
    int* cursor = ideg;
    float* t2  = aggA;
    float* t3  = aggB;
    float* t1a = aggA;                      // [NA,16] (t2 dead by then)
    float* t1b = aggA + (size_t)NA*DOUT;    // spills into aggB region: NA*32 floats total = 12.8MB < 51.2MB
    float* out = (float*)d_out;

    const int* offsR[4] = {offs_all, offs_all + ND, offs_all + 2*ND, offs_all + 2*ND + NA};

    // ---- 1. relation weights ----
    k_weights<<<(HDIM*HDIM+255)/256, 256, 0, stream>>>(basis0, coef0, W00, W01, 0, 1, HDIM*HDIM);
    k_weights<<<(HDIM*HDIM+255)/256, 256, 0, stream>>>(basis1, coef1, W12, W13, 2, 3, HDIM*HDIM);
    k_weights<<<(HDIM*DOUT+255)/256, 256, 0, stream>>>(basis2, coef2, W20, W21, 0, 1, HDIM*DOUT);

    // ---- 2. batched CSR build (concatenated node space, global scan) ----
    {
        int nb = (NODE_TOT + 1023) / 1024;
        hipMemsetAsync(ideg, 0, (size_t)NODE_TOT * 4, stream);
        k_degree4<<<(Etot+255)/256, 256, 0, stream>>>(d0, d1, d2, d3, E0, E1, E2, E3, ideg);
        k_scan1<<<nb, 1024, 0, stream>>>(ideg, offs_all, bsum, NODE_TOT);
        k_scan2<<<1, 1024, 0, stream>>>(bsum, nb);
        k_scan3<<<nb, 1024, 0, stream>>>(offs_all, bsum, NODE_TOT);
        k_copy_i<<<(NODE_TOT+255)/256, 256, 0, stream>>>(offs_all, cursor, NODE_TOT);
        k_fill4<<<(Etot+255)/256, 256, 0, stream>>>(s0, d0, s1, d1, s2, d2, s3, d3,
                                                    E0, E1, E2, E3, cursor, csr_all);
    }

    // ---- 3. layer 0: h0d = relu(mean_e0(feat_a) @ W00 + mean_e1(feat_b) @ W01 + bias0) ----
    k_gather128<<<(ND+3)/4, 256, 0, stream>>>(feat_a, offsR[0], csr_all, nullptr, 0, aggA, ND);
    k_gather128<<<(ND+3)/4, 256, 0, stream>>>(feat_b, offsR[1], csr_all, nullptr, 0, aggB, ND);
    k_gemm2_64<<<(ND+63)/64, 256, 0, stream>>>(aggA, aggB, W00, W01, bias0, h0d, ND);

    // ---- 4. layer 1 (transform-then-aggregate): t2 = h0d@W12, t3 = h0d@W13 (50k rows) ----
    k_gemm1_64<<<(ND+63)/64, 256, 0, stream>>>(h0d, W12, nullptr, 0, t2, ND);
    k_gemm1_64<<<(ND+63)/64, 256, 0, stream>>>(h0d, W13, nullptr, 0, t3, ND);
    // h1a = relu(mean_e2(t2) + bias1), h1b = relu(mean_e3(t3) + bias1)  (fused epilogue)
    k_gather128<<<(NA+3)/4, 256, 0, stream>>>(t2, offsR[2], csr_all, bias1, 1, h1a, NA);
    k_gather128<<<(NB+3)/4, 256, 0, stream>>>(t3, offsR[3], csr_all, bias1, 1, h1b, NB);

    // ---- 5. layer 2 (transform-then-aggregate, dout=16) ----
    k_trans16<<<(NA+255)/256, 256, 0, stream>>>(h1a, W20, t1a, NA);
    k_trans16<<<(NB+255)/256, 256, 0, stream>>>(h1b, W21, t1b, NB);
    k_gather16_combine<<<(ND+63)/64, 256, 0, stream>>>(t1a, t1b, offsR[0], offsR[1], csr_all,
                                                       bias2, out, ND);
}

// Round 5
// 763.287 us; speedup vs baseline: 2.8167x; 2.8167x over previous
//
#include <hip/hip_runtime.h>

#define NA 100000
#define NB 100000
#define ND 50000
#define HDIM 128
#define DOUT 16
// concatenated dst-node space: rel0 d:[0,ND) rel1 d:[ND,2ND) rel2 a:[2ND,2ND+NA) rel3 b:[2ND+NA,...)
#define NODE_TOT (2*ND + NA + NB)

// ---------------- weights: W_r = coef[r,0]*basis[0] + coef[r,1]*basis[1] ----------------
__global__ __launch_bounds__(256) void k_weights(const float* __restrict__ basis,
                                                 const float* __restrict__ coef,
                                                 float* __restrict__ W0, float* __restrict__ W1,
                                                 int r0, int r1, int n) {
    int i = blockIdx.x * 256 + threadIdx.x;
    if (i >= n) return;
    float b0 = basis[i], b1 = basis[n + i];
    W0[i] = coef[r0*2+0]*b0 + coef[r0*2+1]*b1;
    W1[i] = coef[r1*2+0]*b0 + coef[r1*2+1]*b1;
}

// ---------------- batched CSR build over all 4 relations ----------------
__global__ __launch_bounds__(256) void k_degree4(const int* __restrict__ d0, const int* __restrict__ d1,
                                                 const int* __restrict__ d2, const int* __restrict__ d3,
                                                 int E0, int E1, int E2, int E3,
                                                 int* __restrict__ deg) {
    int g = blockIdx.x * 256 + threadIdx.x;
    int node;
    if (g < E0)                node = d0[g];
    else if (g < E0+E1)        node = ND + d1[g-E0];
    else if (g < E0+E1+E2)     node = 2*ND + d2[g-E0-E1];
    else if (g < E0+E1+E2+E3)  node = 2*ND+NA + d3[g-E0-E1-E2];
    else return;
    atomicAdd(&deg[node], 1);
}

__global__ __launch_bounds__(1024) void k_scan1(const int* __restrict__ deg,
                                                int* __restrict__ offs,
                                                int* __restrict__ bsum, int N) {
    __shared__ int sh[1024];
    int i = blockIdx.x * 1024 + threadIdx.x;
    int v = (i < N) ? deg[i] : 0;
    sh[threadIdx.x] = v;
    __syncthreads();
    for (int off = 1; off < 1024; off <<= 1) {
        int t = (threadIdx.x >= off) ? sh[threadIdx.x - off] : 0;
        __syncthreads();
        sh[threadIdx.x] += t;
        __syncthreads();
    }
    if (i < N) offs[i + 1] = sh[threadIdx.x];
    if (threadIdx.x == 1023) bsum[blockIdx.x] = sh[1023];
    if (i == 0) offs[0] = 0;
}

__global__ __launch_bounds__(1024) void k_scan2(int* __restrict__ bsum, int nb) {
    __shared__ int sh[1024];
    int t = threadIdx.x;
    sh[t] = (t < nb) ? bsum[t] : 0;
    __syncthreads();
    for (int off = 1; off < 1024; off <<= 1) {
        int v = (t >= off) ? sh[t - off] : 0;
        __syncthreads();
        sh[t] += v;
        __syncthreads();
    }
    if (t < nb) bsum[t] = sh[t];
}

__global__ __launch_bounds__(1024) void k_scan3(int* __restrict__ offs,
                                                const int* __restrict__ bsum, int N) {
    int i = blockIdx.x * 1024 + threadIdx.x;
    if (blockIdx.x > 0 && i < N) offs[i + 1] += bsum[blockIdx.x - 1];
}

__global__ __launch_bounds__(256) void k_copy_i(const int* __restrict__ a,
                                                int* __restrict__ b, int N) {
    int i = blockIdx.x * 256 + threadIdx.x;
    if (i < N) b[i] = a[i];
}

__global__ __launch_bounds__(256) void k_fill4(const int* __restrict__ s0p, const int* __restrict__ d0p,
                                               const int* __restrict__ s1p, const int* __restrict__ d1p,
                                               const int* __restrict__ s2p, const int* __restrict__ d2p,
                                               const int* __restrict__ s3p, const int* __restrict__ d3p,
                                               int E0, int E1, int E2, int E3,
                                               int* __restrict__ cursor, int* __restrict__ csr) {
    int g = blockIdx.x * 256 + threadIdx.x;
    int node, src;
    if (g < E0)                { node = d0p[g];                    src = s0p[g]; }
    else if (g < E0+E1)        { node = ND + d1p[g-E0];            src = s1p[g-E0]; }
    else if (g < E0+E1+E2)     { node = 2*ND + d2p[g-E0-E1];       src = s2p[g-E0-E1]; }
    else if (g < E0+E1+E2+E3)  { node = 2*ND+NA + d3p[g-E0-E1-E2]; src = s3p[g-E0-E1-E2]; }
    else return;
    int p = atomicAdd(&cursor[node], 1);
    csr[p] = src;
}

// ---------------- gather (CSR, mean-normalized, optional bias+relu) ----------------
__global__ __launch_bounds__(256) void k_gather128(const float* __restrict__ feat,
                                                   const int* __restrict__ offs,
                                                   const int* __restrict__ csr,
                                                   const float* __restrict__ bias, int relu,
                                                   float* __restrict__ out, int nrows) {
    int w = threadIdx.x >> 6;
    int lane = threadIdx.x & 63;
    int row = blockIdx.x * 4 + w;
    if (row >= nrows) return;
    int s0 = offs[row], s1 = offs[row + 1];
    float2 acc = make_float2(0.f, 0.f);
    int j = s0;
    for (; j + 1 < s1; j += 2) {
        int sA = csr[j], sB = csr[j + 1];
        const float2 a = *reinterpret_cast<const float2*>(feat + (size_t)sA*HDIM + lane*2);
        const float2 b = *reinterpret_cast<const float2*>(feat + (size_t)sB*HDIM + lane*2);
        acc.x += a.x + b.x; acc.y += a.y + b.y;
    }
    if (j < s1) {
        int sA = csr[j];
        const float2 a = *reinterpret_cast<const float2*>(feat + (size_t)sA*HDIM + lane*2);
        acc.x += a.x; acc.y += a.y;
    }
    float sc = 1.0f / fmaxf((float)(s1 - s0), 1.0f);
    float vx = acc.x * sc, vy = acc.y * sc;
    if (bias) {
        const float2 bi = *reinterpret_cast<const float2*>(bias + lane*2);
        vx += bi.x; vy += bi.y;
    }
    if (relu) { vx = fmaxf(vx, 0.f); vy = fmaxf(vy, 0.f); }
    *reinterpret_cast<float2*>(out + (size_t)row*HDIM + lane*2) = make_float2(vx, vy);
}

// ---------------- LDS-tiled GEMM, 64x128 tile, 4x8 acc/thread ----------------
// A staged transposed As[k][row] pitch 68; W staged Ws[k][col] pitch 132.
// A global load: row=t>>2, k=(t&3)*4 -> 64B-contiguous per 4 lanes.
// NOTE: no min-waves clause — round 4's (256,4) forced VGPR=64 and spilled the
// accumulators to scratch (4.5 GB HBM traffic/dispatch, 1.58 ms). Let RA breathe.
__global__ __launch_bounds__(256) void k_gemm1_64(const float* __restrict__ A,
                                                  const float* __restrict__ W,
                                                  const float* __restrict__ bias, int relu,
                                                  float* __restrict__ out, int nrows) {
    __shared__ float As[16 * 68];
    __shared__ float Ws[16 * 132];
    const int t = threadIdx.x;
    const int tx = t & 15, ty = t >> 4;
    const int row0 = blockIdx.x * 64;
    const int ar = t >> 2, ak = (t & 3) * 4;
    const int wk = t >> 4, wc = t & 15;
    float acc[4][8];
    #pragma unroll
    for (int i = 0; i < 4; ++i)
        #pragma unroll
        for (int j = 0; j < 8; ++j) acc[i][j] = 0.f;
    const bool arow_ok = (row0 + ar) < nrows;
    const float* Arow = A + (size_t)(row0 + ar) * HDIM;

    for (int k0 = 0; k0 < HDIM; k0 += 16) {
        float4 av = make_float4(0.f,0.f,0.f,0.f);
        if (arow_ok) av = *(const float4*)(Arow + k0 + ak);
        const float4 wv0 = *(const float4*)(W + (size_t)(k0 + wk)*HDIM + wc*4);
        const float4 wv1 = *(const float4*)(W + (size_t)(k0 + wk)*HDIM + 64 + wc*4);
        __syncthreads();
        As[(ak+0)*68 + ar] = av.x; As[(ak+1)*68 + ar] = av.y;
        As[(ak+2)*68 + ar] = av.z; As[(ak+3)*68 + ar] = av.w;
        *(float4*)(Ws + wk*132 + wc*4) = wv0;
        *(float4*)(Ws + wk*132 + 64 + wc*4) = wv1;
        __syncthreads();
        #pragma unroll
        for (int k = 0; k < 16; ++k) {
            const float4 a0 = *(const float4*)(As + k*68 + ty*4);
            const float4 w0 = *(const float4*)(Ws + k*132 + tx*4);
            const float4 w1 = *(const float4*)(Ws + k*132 + 64 + tx*4);
            const float a[4] = {a0.x,a0.y,a0.z,a0.w};
            const float w[8] = {w0.x,w0.y,w0.z,w0.w,w1.x,w1.y,w1.z,w1.w};
            #pragma unroll
            for (int i = 0; i < 4; ++i)
                #pragma unroll
                for (int j = 0; j < 8; ++j)
                    acc[i][j] += a[i]*w[j];
        }
    }
    float bj[8] = {0,0,0,0,0,0,0,0};
    if (bias) {
        const float4 b0 = *(const float4*)(bias + tx*4);
        const float4 b1 = *(const float4*)(bias + 64 + tx*4);
        bj[0]=b0.x; bj[1]=b0.y; bj[2]=b0.z; bj[3]=b0.w;
        bj[4]=b1.x; bj[5]=b1.y; bj[6]=b1.z; bj[7]=b1.w;
    }
    #pragma unroll
    for (int i = 0; i < 4; ++i) {
        int r = row0 + ty*4 + i;
        if (r >= nrows) continue;
        float o[8];
        #pragma unroll
        for (int j = 0; j < 8; ++j) {
            float v = acc[i][j] + bj[j];
            o[j] = relu ? fmaxf(v, 0.f) : v;
        }
        *(float4*)(out + (size_t)r*HDIM + tx*4)      = make_float4(o[0],o[1],o[2],o[3]);
        *(float4*)(out + (size_t)r*HDIM + 64 + tx*4) = make_float4(o[4],o[5],o[6],o[7]);
    }
}

__global__ __launch_bounds__(256) void k_gemm2_64(const float* __restrict__ A, const float* __restrict__ B,
                                                  const float* __restrict__ WA, const float* __restrict__ WB,
                                                  const float* __restrict__ bias,
                                                  float* __restrict__ out, int nrows) {
    __shared__ float As[16 * 68];
    __shared__ float Bs[16 * 68];
    __shared__ float WAs[16 * 132];
    __shared__ float WBs[16 * 132];
    const int t = threadIdx.x;
    const int tx = t & 15, ty = t >> 4;
    const int row0 = blockIdx.x * 64;
    const int ar = t >> 2, ak = (t & 3) * 4;
    const int wk = t >> 4, wc = t & 15;
    float acc[4][8];
    #pragma unroll
    for (int i = 0; i < 4; ++i)
        #pragma unroll
        for (int j = 0; j < 8; ++j) acc[i][j] = 0.f;
    const bool arow_ok = (row0 + ar) < nrows;
    const float* Arow = A + (size_t)(row0 + ar) * HDIM;
    const float* Brow = B + (size_t)(row0 + ar) * HDIM;

    for (int k0 = 0; k0 < HDIM; k0 += 16) {
        float4 av = make_float4(0.f,0.f,0.f,0.f), bv = av;
        if (arow_ok) {
            av = *(const float4*)(Arow + k0 + ak);
            bv = *(const float4*)(Brow + k0 + ak);
        }
        const float4 wa0 = *(const float4*)(WA + (size_t)(k0 + wk)*HDIM + wc*4);
        const float4 wa1 = *(const float4*)(WA + (size_t)(k0 + wk)*HDIM + 64 + wc*4);
        const float4 wb0 = *(const float4*)(WB + (size_t)(k0 + wk)*HDIM + wc*4);
        const float4 wb1 = *(const float4*)(WB + (size_t)(k0 + wk)*HDIM + 64 + wc*4);
        __syncthreads();
        As[(ak+0)*68 + ar] = av.x; As[(ak+1)*68 + ar] = av.y;
        As[(ak+2)*68 + ar] = av.z; As[(ak+3)*68 + ar] = av.w;
        Bs[(ak+0)*68 + ar] = bv.x; Bs[(ak+1)*68 + ar] = bv.y;
        Bs[(ak+2)*68 + ar] = bv.z; Bs[(ak+3)*68 + ar] = bv.w;
        *(float4*)(WAs + wk*132 + wc*4) = wa0;
        *(float4*)(WAs + wk*132 + 64 + wc*4) = wa1;
        *(float4*)(WBs + wk*132 + wc*4) = wb0;
        *(float4*)(WBs + wk*132 + 64 + wc*4) = wb1;
        __syncthreads();
        #pragma unroll
        for (int k = 0; k < 16; ++k) {
            const float4 a0 = *(const float4*)(As + k*68 + ty*4);
            const float4 b0 = *(const float4*)(Bs + k*68 + ty*4);
            const float4 x0 = *(const float4*)(WAs + k*132 + tx*4);
            const float4 x1 = *(const float4*)(WAs + k*132 + 64 + tx*4);
            const float4 y0 = *(const float4*)(WBs + k*132 + tx*4);
            const float4 y1 = *(const float4*)(WBs + k*132 + 64 + tx*4);
            const float a[4]  = {a0.x,a0.y,a0.z,a0.w};
            const float b[4]  = {b0.x,b0.y,b0.z,b0.w};
            const float wa[8] = {x0.x,x0.y,x0.z,x0.w,x1.x,x1.y,x1.z,x1.w};
            const float wb[8] = {y0.x,y0.y,y0.z,y0.w,y1.x,y1.y,y1.z,y1.w};
            #pragma unroll
            for (int i = 0; i < 4; ++i)
                #pragma unroll
                for (int j = 0; j < 8; ++j)
                    acc[i][j] += a[i]*wa[j] + b[i]*wb[j];
        }
    }
    const float4 b0 = *(const float4*)(bias + tx*4);
    const float4 b1 = *(const float4*)(bias + 64 + tx*4);
    const float bj[8] = {b0.x,b0.y,b0.z,b0.w,b1.x,b1.y,b1.z,b1.w};
    #pragma unroll
    for (int i = 0; i < 4; ++i) {
        int r = row0 + ty*4 + i;
        if (r >= nrows) continue;
        float o[8];
        #pragma unroll
        for (int j = 0; j < 8; ++j) o[j] = fmaxf(acc[i][j] + bj[j], 0.f);
        *(float4*)(out + (size_t)r*HDIM + tx*4)      = make_float4(o[0],o[1],o[2],o[3]);
        *(float4*)(out + (size_t)r*HDIM + 64 + tx*4) = make_float4(o[4],o[5],o[6],o[7]);
    }
}

// transform h1 by W2 ([128,16], LDS-staged): one thread per row
__global__ __launch_bounds__(256) void k_trans16(const float* __restrict__ A,
                                                 const float* __restrict__ W,
                                                 float* __restrict__ out, int nrows) {
    __shared__ float Ws[HDIM * DOUT];
    const int t = threadIdx.x;
    *(float4*)(Ws + t*8)     = *(const float4*)(W + t*8);
    *(float4*)(Ws + t*8 + 4) = *(const float4*)(W + t*8 + 4);
    __syncthreads();
    int row = blockIdx.x * 256 + t;
    if (row >= nrows) return;
    const float* a = A + (size_t)row * HDIM;
    float acc[DOUT];
    #pragma unroll
    for (int j = 0; j < DOUT; ++j) acc[j] = 0.f;
    #pragma unroll 4
    for (int k = 0; k < HDIM; k += 4) {
        const float4 av = *(const float4*)(a + k);
        #pragma unroll
        for (int j = 0; j < DOUT; ++j)
            acc[j] += av.x*Ws[k*DOUT + j] + av.y*Ws[(k+1)*DOUT + j]
                    + av.z*Ws[(k+2)*DOUT + j] + av.w*Ws[(k+3)*DOUT + j];
    }
    #pragma unroll
    for (int j = 0; j < DOUT; j += 4)
        *(float4*)(out + (size_t)row*DOUT + j) = make_float4(acc[j],acc[j+1],acc[j+2],acc[j+3]);
}

// final: out[d] = mean-gather(t0 via rel0) + mean-gather(t1 via rel1) + bias
__global__ __launch_bounds__(256) void k_gather16_combine(const float* __restrict__ t0,
                                                          const float* __restrict__ t1,
                                                          const int* __restrict__ offs0,
                                                          const int* __restrict__ offs1,
                                                          const int* __restrict__ csr,
                                                          const float* __restrict__ bias,
                                                          float* __restrict__ out, int nrows) {
    int t = threadIdx.x;
    int row = blockIdx.x * 64 + (t >> 2);
    if (row >= nrows) return;
    int c = (t & 3) * 4;
    float4 acc = make_float4(0.f, 0.f, 0.f, 0.f);
    int s0 = offs0[row], s1 = offs0[row + 1];
    for (int j = s0; j < s1; ++j) {
        int s = csr[j];
        float4 v = *reinterpret_cast<const float4*>(t0 + (size_t)s*DOUT + c);
        acc.x += v.x; acc.y += v.y; acc.z += v.z; acc.w += v.w;
    }
    float sc = 1.0f / fmaxf((float)(s1 - s0), 1.0f);
    acc.x *= sc; acc.y *= sc; acc.z *= sc; acc.w *= sc;
    float4 acc2 = make_float4(0.f, 0.f, 0.f, 0.f);
    int u0 = offs1[row], u1 = offs1[row + 1];
    for (int j = u0; j < u1; ++j) {
        int s = csr[j];
        float4 v = *reinterpret_cast<const float4*>(t1 + (size_t)s*DOUT + c);
        acc2.x += v.x; acc2.y += v.y; acc2.z += v.z; acc2.w += v.w;
    }
    float sc2 = 1.0f / fmaxf((float)(u1 - u0), 1.0f);
    float4 bi = *reinterpret_cast<const float4*>(bias + c);
    acc.x += acc2.x*sc2 + bi.x; acc.y += acc2.y*sc2 + bi.y;
    acc.z += acc2.z*sc2 + bi.z; acc.w += acc2.w*sc2 + bi.w;
    *reinterpret_cast<float4*>(out + (size_t)row*DOUT + c) = acc;
}

extern "C" void kernel_launch(void* const* d_in, const int* in_sizes, int n_in,
                              void* d_out, int out_size, void* d_ws, size_t ws_size,
                              hipStream_t stream) {
    const float* feat_a = (const float*)d_in[0];
    const float* feat_b = (const float*)d_in[1];
    const float* basis0 = (const float*)d_in[3];
    const float* coef0  = (const float*)d_in[4];
    const float* bias0  = (const float*)d_in[5];
    const float* basis1 = (const float*)d_in[6];
    const float* coef1  = (const float*)d_in[7];
    const float* bias1  = (const float*)d_in[8];
    const float* basis2 = (const float*)d_in[9];
    const float* coef2  = (const float*)d_in[10];
    const float* bias2  = (const float*)d_in[11];
    const int* s0 = (const int*)d_in[12]; const int* d0 = (const int*)d_in[13];
    const int* s1 = (const int*)d_in[14]; const int* d1 = (const int*)d_in[15];
    const int* s2 = (const int*)d_in[16]; const int* d2 = (const int*)d_in[17];
    const int* s3 = (const int*)d_in[18]; const int* d3 = (const int*)d_in[19];
    const int E0 = in_sizes[12], E1 = in_sizes[14], E2 = in_sizes[16], E3 = in_sizes[18];
    const int Etot = E0 + E1 + E2 + E3;

    // ---- workspace carve-up ----
    char* base = (char*)d_ws;
    auto alloc = [&](size_t bytes) { char* p = base; base += (bytes + 255) & ~(size_t)255; return p; };
    float* W00 = (float*)alloc(HDIM*HDIM*4);
    float* W01 = (float*)alloc(HDIM*HDIM*4);
    float* W12 = (float*)alloc(HDIM*HDIM*4);
    float* W13 = (float*)alloc(HDIM*HDIM*4);
    float* W20 = (float*)alloc(HDIM*DOUT*4);
    float* W21 = (float*)alloc(HDIM*DOUT*4);
    int* offs_all = (int*)alloc((NODE_TOT + 1) * 4);
    int* csr_all  = (int*)alloc((size_t)Etot * 4);
    int* bsum     = (int*)alloc(2048 * 4);
    int* ideg     = (int*)alloc(NODE_TOT * 4);     // reused as cursor
    float* aggA = (float*)alloc((size_t)ND*HDIM*4);   // layer0 aggA -> t2 -> t1a/t1b
    float* aggB = (float*)alloc((size_t)ND*HDIM*4);   // layer0 aggB -> t3
    float* h0d  = (float*)alloc((size_t)ND*HDIM*4);
    float* h1a  = (float*)alloc((size_t)NA*HDIM*4);
    float* h1b  = (float*)alloc((size_t)NB*HDIM*4);
    int* cursor = ideg;
    float* t2  = aggA;
    float* t3  = aggB;
    float* t1a = aggA;                      // [NA,16] (t2 dead by then)
    float* t1b = aggA + (size_t)NA*DOUT;    // spills into aggB region: NA*32 floats = 12.8MB < 51.2MB
    float* out = (float*)d_out;

    const int* offsR[4] = {offs_all, offs_all + ND, offs_all + 2*ND, offs_all + 2*ND + NA};

    // ---- 1. relation weights ----
    k_weights<<<(HDIM*HDIM+255)/256, 256, 0, stream>>>(basis0, coef0, W00, W01, 0, 1, HDIM*HDIM);
    k_weights<<<(HDIM*HDIM+255)/256, 256, 0, stream>>>(basis1, coef1, W12, W13, 2, 3, HDIM*HDIM);
    k_weights<<<(HDIM*DOUT+255)/256, 256, 0, stream>>>(basis2, coef2, W20, W21, 0, 1, HDIM*DOUT);

    // ---- 2. batched CSR build (concatenated node space, global scan) ----
    {
        int nb = (NODE_TOT + 1023) / 1024;
        hipMemsetAsync(ideg, 0, (size_t)NODE_TOT * 4, stream);
        k_degree4<<<(Etot+255)/256, 256, 0, stream>>>(d0, d1, d2, d3, E0, E1, E2, E3, ideg);
        k_scan1<<<nb, 1024, 0, stream>>>(ideg, offs_all, bsum, NODE_TOT);
        k_scan2<<<1, 1024, 0, stream>>>(bsum, nb);
        k_scan3<<<nb, 1024, 0, stream>>>(offs_all, bsum, NODE_TOT);
        k_copy_i<<<(NODE_TOT+255)/256, 256, 0, stream>>>(offs_all, cursor, NODE_TOT);
        k_fill4<<<(Etot+255)/256, 256, 0, stream>>>(s0, d0, s1, d1, s2, d2, s3, d3,
                                                    E0, E1, E2, E3, cursor, csr_all);
    }

    // ---- 3. layer 0: h0d = relu(mean_e0(feat_a) @ W00 + mean_e1(feat_b) @ W01 + bias0) ----
    k_gather128<<<(ND+3)/4, 256, 0, stream>>>(feat_a, offsR[0], csr_all, nullptr, 0, aggA, ND);
    k_gather128<<<(ND+3)/4, 256, 0, stream>>>(feat_b, offsR[1], csr_all, nullptr, 0, aggB, ND);
    k_gemm2_64<<<(ND+63)/64, 256, 0, stream>>>(aggA, aggB, W00, W01, bias0, h0d, ND);

    // ---- 4. layer 1 (transform-then-aggregate): t2 = h0d@W12, t3 = h0d@W13 (50k rows) ----
    k_gemm1_64<<<(ND+63)/64, 256, 0, stream>>>(h0d, W12, nullptr, 0, t2, ND);
    k_gemm1_64<<<(ND+63)/64, 256, 0, stream>>>(h0d, W13, nullptr, 0, t3, ND);
    // h1a = relu(mean_e2(t2) + bias1), h1b = relu(mean_e3(t3) + bias1)  (fused epilogue)
    k_gather128<<<(NA+3)/4, 256, 0, stream>>>(t2, offsR[2], csr_all, bias1, 1, h1a, NA);
    k_gather128<<<(NB+3)/4, 256, 0, stream>>>(t3, offsR[3], csr_all, bias1, 1, h1b, NB);

    // ---- 5. layer 2 (transform-then-aggregate, dout=16) ----
    k_trans16<<<(NA+255)/256, 256, 0, stream>>>(h1a, W20, t1a, NA);
    k_trans16<<<(NB+255)/256, 256, 0, stream>>>(h1b, W21, t1b, NB);
    k_gather16_combine<<<(ND+63)/64, 256, 0, stream>>>(t1a, t1b, offsR[0], offsR[1], csr_all,
                                                       bias2, out, ND);
}

// Round 6
// 730.470 us; speedup vs baseline: 2.9432x; 1.0449x over previous
//
#include <hip/hip_runtime.h>

#define NA 100000
#define NB 100000
#define ND 50000
#define HDIM 128
#define DOUT 16
// concatenated dst-node space: rel0 d:[0,ND) rel1 d:[ND,2ND) rel2 a:[2ND,2ND+NA) rel3 b:[2ND+NA,...)
#define NODE_TOT (2*ND + NA + NB)

__device__ __forceinline__ unsigned short f2bf(float f) {
    unsigned u = __float_as_uint(f);
    return (unsigned short)((u + 0x7fffu + ((u >> 16) & 1u)) >> 16);
}

// ---------------- weights: W_r = coef[r,0]*basis[0] + coef[r,1]*basis[1] ----------------
__global__ __launch_bounds__(256) void k_weights(const float* __restrict__ basis,
                                                 const float* __restrict__ coef,
                                                 float* __restrict__ W0, float* __restrict__ W1,
                                                 int r0, int r1, int n) {
    int i = blockIdx.x * 256 + threadIdx.x;
    if (i >= n) return;
    float b0 = basis[i], b1 = basis[n + i];
    W0[i] = coef[r0*2+0]*b0 + coef[r0*2+1]*b1;
    W1[i] = coef[r1*2+0]*b0 + coef[r1*2+1]*b1;
}

// ---------------- fp32 -> bf16 conversion (8 elems/thread) ----------------
__global__ __launch_bounds__(256) void k_cvt_bf16(const float* __restrict__ in,
                                                  unsigned int* __restrict__ out, int n8) {
    int i = blockIdx.x * 256 + threadIdx.x;
    if (i >= n8) return;
    const float4 a = *(const float4*)(in + (size_t)i*8);
    const float4 b = *(const float4*)(in + (size_t)i*8 + 4);
    uint4 p;
    p.x = (unsigned)f2bf(a.x) | ((unsigned)f2bf(a.y) << 16);
    p.y = (unsigned)f2bf(a.z) | ((unsigned)f2bf(a.w) << 16);
    p.z = (unsigned)f2bf(b.x) | ((unsigned)f2bf(b.y) << 16);
    p.w = (unsigned)f2bf(b.z) | ((unsigned)f2bf(b.w) << 16);
    *(uint4*)(out + (size_t)i*4) = p;
}

// ---------------- batched CSR build over all 4 relations ----------------
__global__ __launch_bounds__(256) void k_degree4(const int* __restrict__ d0, const int* __restrict__ d1,
                                                 const int* __restrict__ d2, const int* __restrict__ d3,
                                                 int E0, int E1, int E2, int E3,
                                                 int* __restrict__ deg) {
    int g = blockIdx.x * 256 + threadIdx.x;
    int node;
    if (g < E0)                node = d0[g];
    else if (g < E0+E1)        node = ND + d1[g-E0];
    else if (g < E0+E1+E2)     node = 2*ND + d2[g-E0-E1];
    else if (g < E0+E1+E2+E3)  node = 2*ND+NA + d3[g-E0-E1-E2];
    else return;
    atomicAdd(&deg[node], 1);
}

__global__ __launch_bounds__(1024) void k_scan1(const int* __restrict__ deg,
                                                int* __restrict__ offs,
                                                int* __restrict__ bsum, int N) {
    __shared__ int sh[1024];
    int i = blockIdx.x * 1024 + threadIdx.x;
    int v = (i < N) ? deg[i] : 0;
    sh[threadIdx.x] = v;
    __syncthreads();
    for (int off = 1; off < 1024; off <<= 1) {
        int t = (threadIdx.x >= off) ? sh[threadIdx.x - off] : 0;
        __syncthreads();
        sh[threadIdx.x] += t;
        __syncthreads();
    }
    if (i < N) offs[i + 1] = sh[threadIdx.x];
    if (threadIdx.x == 1023) bsum[blockIdx.x] = sh[1023];
    if (i == 0) offs[0] = 0;
}

__global__ __launch_bounds__(1024) void k_scan2(int* __restrict__ bsum, int nb) {
    __shared__ int sh[1024];
    int t = threadIdx.x;
    sh[t] = (t < nb) ? bsum[t] : 0;
    __syncthreads();
    for (int off = 1; off < 1024; off <<= 1) {
        int v = (t >= off) ? sh[t - off] : 0;
        __syncthreads();
        sh[t] += v;
        __syncthreads();
    }
    if (t < nb) bsum[t] = sh[t];
}

__global__ __launch_bounds__(1024) void k_scan3(int* __restrict__ offs,
                                                const int* __restrict__ bsum, int N) {
    int i = blockIdx.x * 1024 + threadIdx.x;
    if (blockIdx.x > 0 && i < N) offs[i + 1] += bsum[blockIdx.x - 1];
}

__global__ __launch_bounds__(256) void k_copy_i(const int* __restrict__ a,
                                                int* __restrict__ b, int N) {
    int i = blockIdx.x * 256 + threadIdx.x;
    if (i < N) b[i] = a[i];
}

__global__ __launch_bounds__(256) void k_fill4(const int* __restrict__ s0p, const int* __restrict__ d0p,
                                               const int* __restrict__ s1p, const int* __restrict__ d1p,
                                               const int* __restrict__ s2p, const int* __restrict__ d2p,
                                               const int* __restrict__ s3p, const int* __restrict__ d3p,
                                               int E0, int E1, int E2, int E3,
                                               int* __restrict__ cursor, int* __restrict__ csr) {
    int g = blockIdx.x * 256 + threadIdx.x;
    int node, src;
    if (g < E0)                { node = d0p[g];                    src = s0p[g]; }
    else if (g < E0+E1)        { node = ND + d1p[g-E0];            src = s1p[g-E0]; }
    else if (g < E0+E1+E2)     { node = 2*ND + d2p[g-E0-E1];       src = s2p[g-E0-E1]; }
    else if (g < E0+E1+E2+E3)  { node = 2*ND+NA + d3p[g-E0-E1-E2]; src = s3p[g-E0-E1-E2]; }
    else return;
    int p = atomicAdd(&cursor[node], 1);
    csr[p] = src;
}

// ---------------- gather (bf16 table, CSR, mean): one wave per dst row ----------------
// table row = 64 uints (128 bf16). lane handles channels 2l, 2l+1. Output fp32.
__global__ __launch_bounds__(256) void k_gather128_bf(const unsigned int* __restrict__ tbl,
                                                      const int* __restrict__ offs,
                                                      const int* __restrict__ csr,
                                                      float* __restrict__ out, int nrows) {
    int w = threadIdx.x >> 6;
    int lane = threadIdx.x & 63;
    int row = blockIdx.x * 4 + w;
    if (row >= nrows) return;
    int s0 = offs[row], s1 = offs[row + 1];
    float ax = 0.f, ay = 0.f;
    int j = s0;
    for (; j + 1 < s1; j += 2) {
        unsigned u1 = tbl[(size_t)csr[j]*64 + lane];
        unsigned u2 = tbl[(size_t)csr[j+1]*64 + lane];
        ax += __uint_as_float(u1 << 16) + __uint_as_float(u2 << 16);
        ay += __uint_as_float(u1 & 0xffff0000u) + __uint_as_float(u2 & 0xffff0000u);
    }
    if (j < s1) {
        unsigned u1 = tbl[(size_t)csr[j]*64 + lane];
        ax += __uint_as_float(u1 << 16);
        ay += __uint_as_float(u1 & 0xffff0000u);
    }
    float sc = 1.0f / fmaxf((float)(s1 - s0), 1.0f);
    *reinterpret_cast<float2*>(out + (size_t)row*HDIM + lane*2) = make_float2(ax*sc, ay*sc);
}

// ---------------- fused layer-1 gather + bias + relu + 128->16 transform ----------------
// Per dst row: v = relu(mean_csr(tbl_bf16) + bias); out16[row] = v @ W (128x16).
// Block = 256 thr = 4 waves; each wave owns 4 rows. vbuf pitch 132 breaks conflicts.
__global__ __launch_bounds__(256) void k_gather_trans16(const unsigned int* __restrict__ tbl,
                                                        const int* __restrict__ offs,
                                                        const int* __restrict__ csr,
                                                        const float* __restrict__ bias,
                                                        const float* __restrict__ W,
                                                        float* __restrict__ out16, int nrows) {
    __shared__ float Wl[HDIM * DOUT];     // 8KB, [c*16+j]
    __shared__ float vbuf[16 * 132];      // 8.25KB
    const int t = threadIdx.x;
    *(float4*)(Wl + t*8)     = *(const float4*)(W + t*8);
    *(float4*)(Wl + t*8 + 4) = *(const float4*)(W + t*8 + 4);
    __syncthreads();
    const int w = t >> 6, lane = t & 63;
    const float b0 = bias[2*lane], b1 = bias[2*lane + 1];
    const int rbase = blockIdx.x * 16 + w * 4;
    #pragma unroll
    for (int r = 0; r < 4; ++r) {
        int row = rbase + r;
        if (row < nrows) {
            int s0 = offs[row], s1 = offs[row + 1];
            float ax = 0.f, ay = 0.f;
            int j = s0;
            for (; j + 1 < s1; j += 2) {
                unsigned u1 = tbl[(size_t)csr[j]*64 + lane];
                unsigned u2 = tbl[(size_t)csr[j+1]*64 + lane];
                ax += __uint_as_float(u1 << 16) + __uint_as_float(u2 << 16);
                ay += __uint_as_float(u1 & 0xffff0000u) + __uint_as_float(u2 & 0xffff0000u);
            }
            if (j < s1) {
                unsigned u1 = tbl[(size_t)csr[j]*64 + lane];
                ax += __uint_as_float(u1 << 16);
                ay += __uint_as_float(u1 & 0xffff0000u);
            }
            float sc = 1.0f / fmaxf((float)(s1 - s0), 1.0f);
            float v0 = fmaxf(ax*sc + b0, 0.f);
            float v1 = fmaxf(ay*sc + b1, 0.f);
            *(float2*)(vbuf + (w*4 + r)*132 + 2*lane) = make_float2(v0, v1);
        }
    }
    __syncthreads();
    const int lr = lane >> 4, jj = lane & 15;
    int row = rbase + lr;
    if (row < nrows) {
        const float* vr = vbuf + (w*4 + lr)*132;
        float acc = 0.f;
        #pragma unroll 8
        for (int c = 0; c < HDIM; ++c)
            acc += vr[c] * Wl[c*DOUT + jj];
        out16[(size_t)row*DOUT + jj] = acc;
    }
}

// ---------------- LDS-tiled GEMM, 64x128 tile, 4x8 acc/thread (fp32 out) ----------------
__global__ __launch_bounds__(256) void k_gemm2_64(const float* __restrict__ A, const float* __restrict__ B,
                                                  const float* __restrict__ WA, const float* __restrict__ WB,
                                                  const float* __restrict__ bias,
                                                  float* __restrict__ out, int nrows) {
    __shared__ float As[16 * 68];
    __shared__ float Bs[16 * 68];
    __shared__ float WAs[16 * 132];
    __shared__ float WBs[16 * 132];
    const int t = threadIdx.x;
    const int tx = t & 15, ty = t >> 4;
    const int row0 = blockIdx.x * 64;
    const int ar = t >> 2, ak = (t & 3) * 4;
    const int wk = t >> 4, wc = t & 15;
    float acc[4][8];
    #pragma unroll
    for (int i = 0; i < 4; ++i)
        #pragma unroll
        for (int j = 0; j < 8; ++j) acc[i][j] = 0.f;
    const bool arow_ok = (row0 + ar) < nrows;
    const float* Arow = A + (size_t)(row0 + ar) * HDIM;
    const float* Brow = B + (size_t)(row0 + ar) * HDIM;

    for (int k0 = 0; k0 < HDIM; k0 += 16) {
        float4 av = make_float4(0.f,0.f,0.f,0.f), bv = av;
        if (arow_ok) {
            av = *(const float4*)(Arow + k0 + ak);
            bv = *(const float4*)(Brow + k0 + ak);
        }
        const float4 wa0 = *(const float4*)(WA + (size_t)(k0 + wk)*HDIM + wc*4);
        const float4 wa1 = *(const float4*)(WA + (size_t)(k0 + wk)*HDIM + 64 + wc*4);
        const float4 wb0 = *(const float4*)(WB + (size_t)(k0 + wk)*HDIM + wc*4);
        const float4 wb1 = *(const float4*)(WB + (size_t)(k0 + wk)*HDIM + 64 + wc*4);
        __syncthreads();
        As[(ak+0)*68 + ar] = av.x; As[(ak+1)*68 + ar] = av.y;
        As[(ak+2)*68 + ar] = av.z; As[(ak+3)*68 + ar] = av.w;
        Bs[(ak+0)*68 + ar] = bv.x; Bs[(ak+1)*68 + ar] = bv.y;
        Bs[(ak+2)*68 + ar] = bv.z; Bs[(ak+3)*68 + ar] = bv.w;
        *(float4*)(WAs + wk*132 + wc*4) = wa0;
        *(float4*)(WAs + wk*132 + 64 + wc*4) = wa1;
        *(float4*)(WBs + wk*132 + wc*4) = wb0;
        *(float4*)(WBs + wk*132 + 64 + wc*4) = wb1;
        __syncthreads();
        #pragma unroll
        for (int k = 0; k < 16; ++k) {
            const float4 a0 = *(const float4*)(As + k*68 + ty*4);
            const float4 b0 = *(const float4*)(Bs + k*68 + ty*4);
            const float4 x0 = *(const float4*)(WAs + k*132 + tx*4);
            const float4 x1 = *(const float4*)(WAs + k*132 + 64 + tx*4);
            const float4 y0 = *(const float4*)(WBs + k*132 + tx*4);
            const float4 y1 = *(const float4*)(WBs + k*132 + 64 + tx*4);
            const float a[4]  = {a0.x,a0.y,a0.z,a0.w};
            const float b[4]  = {b0.x,b0.y,b0.z,b0.w};
            const float wa[8] = {x0.x,x0.y,x0.z,x0.w,x1.x,x1.y,x1.z,x1.w};
            const float wb[8] = {y0.x,y0.y,y0.z,y0.w,y1.x,y1.y,y1.z,y1.w};
            #pragma unroll
            for (int i = 0; i < 4; ++i)
                #pragma unroll
                for (int j = 0; j < 8; ++j)
                    acc[i][j] += a[i]*wa[j] + b[i]*wb[j];
        }
    }
    const float4 b0 = *(const float4*)(bias + tx*4);
    const float4 b1 = *(const float4*)(bias + 64 + tx*4);
    const float bj[8] = {b0.x,b0.y,b0.z,b0.w,b1.x,b1.y,b1.z,b1.w};
    #pragma unroll
    for (int i = 0; i < 4; ++i) {
        int r = row0 + ty*4 + i;
        if (r >= nrows) continue;
        float o[8];
        #pragma unroll
        for (int j = 0; j < 8; ++j) o[j] = fmaxf(acc[i][j] + bj[j], 0.f);
        *(float4*)(out + (size_t)r*HDIM + tx*4)      = make_float4(o[0],o[1],o[2],o[3]);
        *(float4*)(out + (size_t)r*HDIM + 64 + tx*4) = make_float4(o[4],o[5],o[6],o[7]);
    }
}

// single-input GEMM, bf16 output (no bias/relu): t = A @ W, [n,128] bf16
__global__ __launch_bounds__(256) void k_gemm1_64_bf(const float* __restrict__ A,
                                                     const float* __restrict__ W,
                                                     unsigned short* __restrict__ out, int nrows) {
    __shared__ float As[16 * 68];
    __shared__ float Ws[16 * 132];
    const int t = threadIdx.x;
    const int tx = t & 15, ty = t >> 4;
    const int row0 = blockIdx.x * 64;
    const int ar = t >> 2, ak = (t & 3) * 4;
    const int wk = t >> 4, wc = t & 15;
    float acc[4][8];
    #pragma unroll
    for (int i = 0; i < 4; ++i)
        #pragma unroll
        for (int j = 0; j < 8; ++j) acc[i][j] = 0.f;
    const bool arow_ok = (row0 + ar) < nrows;
    const float* Arow = A + (size_t)(row0 + ar) * HDIM;

    for (int k0 = 0; k0 < HDIM; k0 += 16) {
        float4 av = make_float4(0.f,0.f,0.f,0.f);
        if (arow_ok) av = *(const float4*)(Arow + k0 + ak);
        const float4 wv0 = *(const float4*)(W + (size_t)(k0 + wk)*HDIM + wc*4);
        const float4 wv1 = *(const float4*)(W + (size_t)(k0 + wk)*HDIM + 64 + wc*4);
        __syncthreads();
        As[(ak+0)*68 + ar] = av.x; As[(ak+1)*68 + ar] = av.y;
        As[(ak+2)*68 + ar] = av.z; As[(ak+3)*68 + ar] = av.w;
        *(float4*)(Ws + wk*132 + wc*4) = wv0;
        *(float4*)(Ws + wk*132 + 64 + wc*4) = wv1;
        __syncthreads();
        #pragma unroll
        for (int k = 0; k < 16; ++k) {
            const float4 a0 = *(const float4*)(As + k*68 + ty*4);
            const float4 w0 = *(const float4*)(Ws + k*132 + tx*4);
            const float4 w1 = *(const float4*)(Ws + k*132 + 64 + tx*4);
            const float a[4] = {a0.x,a0.y,a0.z,a0.w};
            const float w[8] = {w0.x,w0.y,w0.z,w0.w,w1.x,w1.y,w1.z,w1.w};
            #pragma unroll
            for (int i = 0; i < 4; ++i)
                #pragma unroll
                for (int j = 0; j < 8; ++j)
                    acc[i][j] += a[i]*w[j];
        }
    }
    #pragma unroll
    for (int i = 0; i < 4; ++i) {
        int r = row0 + ty*4 + i;
        if (r >= nrows) continue;
        ushort4 p0, p1;
        p0.x = f2bf(acc[i][0]); p0.y = f2bf(acc[i][1]); p0.z = f2bf(acc[i][2]); p0.w = f2bf(acc[i][3]);
        p1.x = f2bf(acc[i][4]); p1.y = f2bf(acc[i][5]); p1.z = f2bf(acc[i][6]); p1.w = f2bf(acc[i][7]);
        *(ushort4*)(out + (size_t)r*HDIM + tx*4)      = p0;
        *(ushort4*)(out + (size_t)r*HDIM + 64 + tx*4) = p1;
    }
}

// final: out[d] = mean-gather(t0 via rel0) + mean-gather(t1 via rel1) + bias
__global__ __launch_bounds__(256) void k_gather16_combine(const float* __restrict__ t0,
                                                          const float* __restrict__ t1,
                                                          const int* __restrict__ offs0,
                                                          const int* __restrict__ offs1,
                                                          const int* __restrict__ csr,
                                                          const float* __restrict__ bias,
                                                          float* __restrict__ out, int nrows) {
    int t = threadIdx.x;
    int row = blockIdx.x * 64 + (t >> 2);
    if (row >= nrows) return;
    int c = (t & 3) * 4;
    float4 acc = make_float4(0.f, 0.f, 0.f, 0.f);
    int s0 = offs0[row], s1 = offs0[row + 1];
    for (int j = s0; j < s1; ++j) {
        int s = csr[j];
        float4 v = *reinterpret_cast<const float4*>(t0 + (size_t)s*DOUT + c);
        acc.x += v.x; acc.y += v.y; acc.z += v.z; acc.w += v.w;
    }
    float sc = 1.0f / fmaxf((float)(s1 - s0), 1.0f);
    acc.x *= sc; acc.y *= sc; acc.z *= sc; acc.w *= sc;
    float4 acc2 = make_float4(0.f, 0.f, 0.f, 0.f);
    int u0 = offs1[row], u1 = offs1[row + 1];
    for (int j = u0; j < u1; ++j) {
        int s = csr[j];
        float4 v = *reinterpret_cast<const float4*>(t1 + (size_t)s*DOUT + c);
        acc2.x += v.x; acc2.y += v.y; acc2.z += v.z; acc2.w += v.w;
    }
    float sc2 = 1.0f / fmaxf((float)(u1 - u0), 1.0f);
    float4 bi = *reinterpret_cast<const float4*>(bias + c);
    acc.x += acc2.x*sc2 + bi.x; acc.y += acc2.y*sc2 + bi.y;
    acc.z += acc2.z*sc2 + bi.z; acc.w += acc2.w*sc2 + bi.w;
    *reinterpret_cast<float4*>(out + (size_t)row*DOUT + c) = acc;
}

extern "C" void kernel_launch(void* const* d_in, const int* in_sizes, int n_in,
                              void* d_out, int out_size, void* d_ws, size_t ws_size,
                              hipStream_t stream) {
    const float* feat_a = (const float*)d_in[0];
    const float* feat_b = (const float*)d_in[1];
    const float* basis0 = (const float*)d_in[3];
    const float* coef0  = (const float*)d_in[4];
    const float* bias0  = (const float*)d_in[5];
    const float* basis1 = (const float*)d_in[6];
    const float* coef1  = (const float*)d_in[7];
    const float* bias1  = (const float*)d_in[8];
    const float* basis2 = (const float*)d_in[9];
    const float* coef2  = (const float*)d_in[10];
    const float* bias2  = (const float*)d_in[11];
    const int* s0 = (const int*)d_in[12]; const int* d0 = (const int*)d_in[13];
    const int* s1 = (const int*)d_in[14]; const int* d1 = (const int*)d_in[15];
    const int* s2 = (const int*)d_in[16]; const int* d2 = (const int*)d_in[17];
    const int* s3 = (const int*)d_in[18]; const int* d3 = (const int*)d_in[19];
    const int E0 = in_sizes[12], E1 = in_sizes[14], E2 = in_sizes[16], E3 = in_sizes[18];
    const int Etot = E0 + E1 + E2 + E3;

    // ---- workspace carve-up ----
    char* base = (char*)d_ws;
    auto alloc = [&](size_t bytes) { char* p = base; base += (bytes + 255) & ~(size_t)255; return p; };
    float* W00 = (float*)alloc(HDIM*HDIM*4);
    float* W01 = (float*)alloc(HDIM*HDIM*4);
    float* W12 = (float*)alloc(HDIM*HDIM*4);
    float* W13 = (float*)alloc(HDIM*HDIM*4);
    float* W20 = (float*)alloc(HDIM*DOUT*4);
    float* W21 = (float*)alloc(HDIM*DOUT*4);
    int* offs_all = (int*)alloc((NODE_TOT + 1) * 4);
    int* csr_all  = (int*)alloc((size_t)Etot * 4);
    int* bsum     = (int*)alloc(2048 * 4);
    int* ideg     = (int*)alloc(NODE_TOT * 4);     // reused as cursor
    unsigned int* fa_bf = (unsigned int*)alloc((size_t)NA*HDIM*2);  // bf16 feats
    unsigned int* fb_bf = (unsigned int*)alloc((size_t)NB*HDIM*2);
    unsigned int* t2_bf = (unsigned int*)alloc((size_t)ND*HDIM*2);  // bf16 t-tables
    unsigned int* t3_bf = (unsigned int*)alloc((size_t)ND*HDIM*2);
    float* aggA = (float*)alloc((size_t)ND*HDIM*4);
    float* aggB = (float*)alloc((size_t)ND*HDIM*4);
    float* h0d  = (float*)alloc((size_t)ND*HDIM*4);
    float* t1a  = (float*)alloc((size_t)NA*DOUT*4);
    float* t1b  = (float*)alloc((size_t)NB*DOUT*4);
    int* cursor = ideg;
    float* out = (float*)d_out;

    const int* offsR[4] = {offs_all, offs_all + ND, offs_all + 2*ND, offs_all + 2*ND + NA};

    // ---- 1. relation weights + feat bf16 conversion ----
    k_weights<<<(HDIM*HDIM+255)/256, 256, 0, stream>>>(basis0, coef0, W00, W01, 0, 1, HDIM*HDIM);
    k_weights<<<(HDIM*HDIM+255)/256, 256, 0, stream>>>(basis1, coef1, W12, W13, 2, 3, HDIM*HDIM);
    k_weights<<<(HDIM*DOUT+255)/256, 256, 0, stream>>>(basis2, coef2, W20, W21, 0, 1, HDIM*DOUT);
    k_cvt_bf16<<<(NA*16+255)/256, 256, 0, stream>>>(feat_a, fa_bf, NA*16);
    k_cvt_bf16<<<(NB*16+255)/256, 256, 0, stream>>>(feat_b, fb_bf, NB*16);

    // ---- 2. batched CSR build ----
    {
        int nb = (NODE_TOT + 1023) / 1024;
        hipMemsetAsync(ideg, 0, (size_t)NODE_TOT * 4, stream);
        k_degree4<<<(Etot+255)/256, 256, 0, stream>>>(d0, d1, d2, d3, E0, E1, E2, E3, ideg);
        k_scan1<<<nb, 1024, 0, stream>>>(ideg, offs_all, bsum, NODE_TOT);
        k_scan2<<<1, 1024, 0, stream>>>(bsum, nb);
        k_scan3<<<nb, 1024, 0, stream>>>(offs_all, bsum, NODE_TOT);
        k_copy_i<<<(NODE_TOT+255)/256, 256, 0, stream>>>(offs_all, cursor, NODE_TOT);
        k_fill4<<<(Etot+255)/256, 256, 0, stream>>>(s0, d0, s1, d1, s2, d2, s3, d3,
                                                    E0, E1, E2, E3, cursor, csr_all);
    }

    // ---- 3. layer 0: h0d = relu(mean_e0(feat_a) @ W00 + mean_e1(feat_b) @ W01 + bias0) ----
    k_gather128_bf<<<(ND+3)/4, 256, 0, stream>>>(fa_bf, offsR[0], csr_all, aggA, ND);
    k_gather128_bf<<<(ND+3)/4, 256, 0, stream>>>(fb_bf, offsR[1], csr_all, aggB, ND);
    k_gemm2_64<<<(ND+63)/64, 256, 0, stream>>>(aggA, aggB, W00, W01, bias0, h0d, ND);

    // ---- 4. layer 1 transform (50k rows, bf16 out) ----
    k_gemm1_64_bf<<<(ND+63)/64, 256, 0, stream>>>(h0d, W12, (unsigned short*)t2_bf, ND);
    k_gemm1_64_bf<<<(ND+63)/64, 256, 0, stream>>>(h0d, W13, (unsigned short*)t3_bf, ND);

    // ---- 5. fused layer-1 aggregate + bias/relu + layer-2 transform -> t1a/t1b ----
    k_gather_trans16<<<(NA+15)/16, 256, 0, stream>>>(t2_bf, offsR[2], csr_all, bias1, W20, t1a, NA);
    k_gather_trans16<<<(NB+15)/16, 256, 0, stream>>>(t3_bf, offsR[3], csr_all, bias1, W21, t1b, NB);

    // ---- 6. final combine ----
    k_gather16_combine<<<(ND+63)/64, 256, 0, stream>>>(t1a, t1b, offsR[0], offsR[1], csr_all,
                                                       bias2, out, ND);
}

// Round 7
// 514.181 us; speedup vs baseline: 4.1813x; 1.4206x over previous
//
#include <hip/hip_runtime.h>

#define NA 100000
#define NB 100000
#define ND 50000
#define HDIM 128
#define DOUT 16
// concatenated dst-node space: rel0 d:[0,ND) rel1 d:[ND,2ND) rel2 a:[2ND,2ND+NA) rel3 b:[2ND+NA,...)
#define NODE_TOT (2*ND + NA + NB)
#define BSH 9
#define BKN 512
#define NBUCKET ((NODE_TOT + BKN - 1) >> BSH)   // 586
#define EPB 4096                                 // edges per block, bucket passes

__device__ __forceinline__ unsigned short f2bf(float f) {
    unsigned u = __float_as_uint(f);
    return (unsigned short)((u + 0x7fffu + ((u >> 16) & 1u)) >> 16);
}

struct EdgeT { int node; int src; };
__device__ __forceinline__ EdgeT edge_at(int g,
    const int* __restrict__ s0, const int* __restrict__ d0,
    const int* __restrict__ s1, const int* __restrict__ d1,
    const int* __restrict__ s2, const int* __restrict__ d2,
    const int* __restrict__ s3, const int* __restrict__ d3,
    int E0, int E1, int E2) {
    EdgeT e;
    if (g < E0)             { e.node = d0[g];                    e.src = s0[g]; }
    else if (g < E0+E1)     { e.node = ND + d1[g-E0];            e.src = s1[g-E0]; }
    else if (g < E0+E1+E2)  { e.node = 2*ND + d2[g-E0-E1];       e.src = s2[g-E0-E1]; }
    else                    { e.node = 2*ND+NA + d3[g-E0-E1-E2]; e.src = s3[g-E0-E1-E2]; }
    return e;
}

// ---------------- weights: W_r = coef[r,0]*basis[0] + coef[r,1]*basis[1] ----------------
__global__ __launch_bounds__(256) void k_weights(const float* __restrict__ basis,
                                                 const float* __restrict__ coef,
                                                 float* __restrict__ W0, float* __restrict__ W1,
                                                 int r0, int r1, int n) {
    int i = blockIdx.x * 256 + threadIdx.x;
    if (i >= n) return;
    float b0 = basis[i], b1 = basis[n + i];
    W0[i] = coef[r0*2+0]*b0 + coef[r0*2+1]*b1;
    W1[i] = coef[r1*2+0]*b0 + coef[r1*2+1]*b1;
}

// ---------------- fp32 -> bf16 conversion (8 elems/thread) ----------------
__global__ __launch_bounds__(256) void k_cvt_bf16(const float* __restrict__ in,
                                                  unsigned int* __restrict__ out, int n8) {
    int i = blockIdx.x * 256 + threadIdx.x;
    if (i >= n8) return;
    const float4 a = *(const float4*)(in + (size_t)i*8);
    const float4 b = *(const float4*)(in + (size_t)i*8 + 4);
    uint4 p;
    p.x = (unsigned)f2bf(a.x) | ((unsigned)f2bf(a.y) << 16);
    p.y = (unsigned)f2bf(a.z) | ((unsigned)f2bf(a.w) << 16);
    p.z = (unsigned)f2bf(b.x) | ((unsigned)f2bf(b.y) << 16);
    p.w = (unsigned)f2bf(b.z) | ((unsigned)f2bf(b.w) << 16);
    *(uint4*)(out + (size_t)i*4) = p;
}

// ---------------- bucketed CSR build ----------------
// pass A: bucket histogram, LDS-aggregated
__global__ __launch_bounds__(256) void k_bhist(const int* __restrict__ s0, const int* __restrict__ d0,
                                               const int* __restrict__ s1, const int* __restrict__ d1,
                                               const int* __restrict__ s2, const int* __restrict__ d2,
                                               const int* __restrict__ s3, const int* __restrict__ d3,
                                               int E0, int E1, int E2, int Etot,
                                               int* __restrict__ bcount) {
    __shared__ int h[NBUCKET];
    for (int i = threadIdx.x; i < NBUCKET; i += 256) h[i] = 0;
    __syncthreads();
    int g0 = blockIdx.x * EPB + threadIdx.x;
    #pragma unroll
    for (int i = 0; i < EPB/256; ++i) {
        int g = g0 + i*256;
        if (g < Etot) {
            EdgeT e = edge_at(g, s0,d0,s1,d1,s2,d2,s3,d3, E0,E1,E2);
            atomicAdd(&h[e.node >> BSH], 1);
        }
    }
    __syncthreads();
    for (int i = threadIdx.x; i < NBUCKET; i += 256)
        if (h[i]) atomicAdd(&bcount[i], h[i]);
}

// pass A2: scan 586 bucket counts -> bofs[0..NBUCKET], init gcur = bofs[b]
__global__ __launch_bounds__(1024) void k_bscan(const int* __restrict__ bcount,
                                                int* __restrict__ bofs,
                                                int* __restrict__ gcur) {
    __shared__ int sh[1024];
    int t = threadIdx.x;
    sh[t] = (t < NBUCKET) ? bcount[t] : 0;
    __syncthreads();
    for (int off = 1; off < 1024; off <<= 1) {
        int v = (t >= off) ? sh[t - off] : 0;
        __syncthreads();
        sh[t] += v;
        __syncthreads();
    }
    if (t < NBUCKET) {
        bofs[t + 1] = sh[t];
        int excl = sh[t] - bcount[t];
        gcur[t] = excl;
        if (t == 0) bofs[0] = 0;
    }
}

// pass B: block-level counting sort into pairs[] (bucket-contiguous regions)
__global__ __launch_bounds__(256) void k_bscatter(const int* __restrict__ s0, const int* __restrict__ d0,
                                                  const int* __restrict__ s1, const int* __restrict__ d1,
                                                  const int* __restrict__ s2, const int* __restrict__ d2,
                                                  const int* __restrict__ s3, const int* __restrict__ d3,
                                                  int E0, int E1, int E2, int Etot,
                                                  int* __restrict__ gcur,
                                                  uint2* __restrict__ pairs) {
    __shared__ int hist[NBUCKET];
    __shared__ int base[NBUCKET];
    for (int i = threadIdx.x; i < NBUCKET; i += 256) hist[i] = 0;
    __syncthreads();
    int g0 = blockIdx.x * EPB + threadIdx.x;
    int nd[EPB/256], sr[EPB/256], rk[EPB/256];
    #pragma unroll
    for (int i = 0; i < EPB/256; ++i) {
        int g = g0 + i*256;
        if (g < Etot) {
            EdgeT e = edge_at(g, s0,d0,s1,d1,s2,d2,s3,d3, E0,E1,E2);
            nd[i] = e.node; sr[i] = e.src;
            rk[i] = atomicAdd(&hist[e.node >> BSH], 1);
        } else nd[i] = -1;
    }
    __syncthreads();
    for (int i = threadIdx.x; i < NBUCKET; i += 256)
        if (hist[i]) base[i] = atomicAdd(&gcur[i], hist[i]);
    __syncthreads();
    #pragma unroll
    for (int i = 0; i < EPB/256; ++i) {
        if (nd[i] >= 0) {
            uint2 p; p.x = (unsigned)nd[i]; p.y = (unsigned)sr[i];
            pairs[base[nd[i] >> BSH] + rk[i]] = p;
        }
    }
}

// pass C1: per-bucket degrees via LDS atomics, coalesced store
__global__ __launch_bounds__(256) void k_bdeg(const uint2* __restrict__ pairs,
                                              const int* __restrict__ bofs,
                                              int* __restrict__ deg) {
    __shared__ int ld[BKN];
    int b = blockIdx.x;
    for (int i = threadIdx.x; i < BKN; i += 256) ld[i] = 0;
    __syncthreads();
    int j0 = bofs[b], j1 = bofs[b + 1];
    int nbase = b << BSH;
    for (int j = j0 + threadIdx.x; j < j1; j += 256)
        atomicAdd(&ld[pairs[j].x - nbase], 1);
    __syncthreads();
    for (int i = threadIdx.x; i < BKN && nbase + i < NODE_TOT; i += 256)
        deg[nbase + i] = ld[i];
}

// pass C2: per-bucket fill; cursors in LDS; csr writes confined to bucket window (L2)
__global__ __launch_bounds__(256) void k_bfill(const uint2* __restrict__ pairs,
                                               const int* __restrict__ bofs,
                                               const int* __restrict__ offs,
                                               int* __restrict__ csr) {
    __shared__ int cur[BKN];
    int b = blockIdx.x;
    int nbase = b << BSH;
    for (int i = threadIdx.x; i < BKN && nbase + i < NODE_TOT; i += 256)
        cur[i] = offs[nbase + i];
    __syncthreads();
    int j0 = bofs[b], j1 = bofs[b + 1];
    for (int j = j0 + threadIdx.x; j < j1; j += 256) {
        uint2 e = pairs[j];
        int p = atomicAdd(&cur[e.x - nbase], 1);
        csr[p] = (int)e.y;
    }
}

// ---------------- global scans over NODE_TOT (deg -> offs) ----------------
__global__ __launch_bounds__(1024) void k_scan1(const int* __restrict__ deg,
                                                int* __restrict__ offs,
                                                int* __restrict__ bsum, int N) {
    __shared__ int sh[1024];
    int i = blockIdx.x * 1024 + threadIdx.x;
    int v = (i < N) ? deg[i] : 0;
    sh[threadIdx.x] = v;
    __syncthreads();
    for (int off = 1; off < 1024; off <<= 1) {
        int t = (threadIdx.x >= off) ? sh[threadIdx.x - off] : 0;
        __syncthreads();
        sh[threadIdx.x] += t;
        __syncthreads();
    }
    if (i < N) offs[i + 1] = sh[threadIdx.x];
    if (threadIdx.x == 1023) bsum[blockIdx.x] = sh[1023];
    if (i == 0) offs[0] = 0;
}

__global__ __launch_bounds__(1024) void k_scan2(int* __restrict__ bsum, int nb) {
    __shared__ int sh[1024];
    int t = threadIdx.x;
    sh[t] = (t < nb) ? bsum[t] : 0;
    __syncthreads();
    for (int off = 1; off < 1024; off <<= 1) {
        int v = (t >= off) ? sh[t - off] : 0;
        __syncthreads();
        sh[t] += v;
        __syncthreads();
    }
    if (t < nb) bsum[t] = sh[t];
}

__global__ __launch_bounds__(1024) void k_scan3(int* __restrict__ offs,
                                                const int* __restrict__ bsum, int N) {
    int i = blockIdx.x * 1024 + threadIdx.x;
    if (blockIdx.x > 0 && i < N) offs[i + 1] += bsum[blockIdx.x - 1];
}

// ---------------- gather (bf16 table, CSR, mean): one wave per dst row ----------------
__global__ __launch_bounds__(256) void k_gather128_bf(const unsigned int* __restrict__ tbl,
                                                      const int* __restrict__ offs,
                                                      const int* __restrict__ csr,
                                                      float* __restrict__ out, int nrows) {
    int w = threadIdx.x >> 6;
    int lane = threadIdx.x & 63;
    int row = blockIdx.x * 4 + w;
    if (row >= nrows) return;
    int s0 = offs[row], s1 = offs[row + 1];
    float ax = 0.f, ay = 0.f;
    int j = s0;
    for (; j + 1 < s1; j += 2) {
        unsigned u1 = tbl[(size_t)csr[j]*64 + lane];
        unsigned u2 = tbl[(size_t)csr[j+1]*64 + lane];
        ax += __uint_as_float(u1 << 16) + __uint_as_float(u2 << 16);
        ay += __uint_as_float(u1 & 0xffff0000u) + __uint_as_float(u2 & 0xffff0000u);
    }
    if (j < s1) {
        unsigned u1 = tbl[(size_t)csr[j]*64 + lane];
        ax += __uint_as_float(u1 << 16);
        ay += __uint_as_float(u1 & 0xffff0000u);
    }
    float sc = 1.0f / fmaxf((float)(s1 - s0), 1.0f);
    *reinterpret_cast<float2*>(out + (size_t)row*HDIM + lane*2) = make_float2(ax*sc, ay*sc);
}

// ---------------- fused layer-1 gather + bias + relu + 128->16 transform ----------------
__global__ __launch_bounds__(256) void k_gather_trans16(const unsigned int* __restrict__ tbl,
                                                        const int* __restrict__ offs,
                                                        const int* __restrict__ csr,
                                                        const float* __restrict__ bias,
                                                        const float* __restrict__ W,
                                                        float* __restrict__ out16, int nrows) {
    __shared__ float Wl[HDIM * DOUT];     // 8KB, [c*16+j]
    __shared__ float vbuf[16 * 132];      // 8.25KB
    const int t = threadIdx.x;
    *(float4*)(Wl + t*8)     = *(const float4*)(W + t*8);
    *(float4*)(Wl + t*8 + 4) = *(const float4*)(W + t*8 + 4);
    __syncthreads();
    const int w = t >> 6, lane = t & 63;
    const float b0 = bias[2*lane], b1 = bias[2*lane + 1];
    const int rbase = blockIdx.x * 16 + w * 4;
    #pragma unroll
    for (int r = 0; r < 4; ++r) {
        int row = rbase + r;
        if (row < nrows) {
            int s0 = offs[row], s1 = offs[row + 1];
            float ax = 0.f, ay = 0.f;
            int j = s0;
            for (; j + 1 < s1; j += 2) {
                unsigned u1 = tbl[(size_t)csr[j]*64 + lane];
                unsigned u2 = tbl[(size_t)csr[j+1]*64 + lane];
                ax += __uint_as_float(u1 << 16) + __uint_as_float(u2 << 16);
                ay += __uint_as_float(u1 & 0xffff0000u) + __uint_as_float(u2 & 0xffff0000u);
            }
            if (j < s1) {
                unsigned u1 = tbl[(size_t)csr[j]*64 + lane];
                ax += __uint_as_float(u1 << 16);
                ay += __uint_as_float(u1 & 0xffff0000u);
            }
            float sc = 1.0f / fmaxf((float)(s1 - s0), 1.0f);
            float v0 = fmaxf(ax*sc + b0, 0.f);
            float v1 = fmaxf(ay*sc + b1, 0.f);
            *(float2*)(vbuf + (w*4 + r)*132 + 2*lane) = make_float2(v0, v1);
        }
    }
    __syncthreads();
    const int lr = lane >> 4, jj = lane & 15;
    int row = rbase + lr;
    if (row < nrows) {
        const float* vr = vbuf + (w*4 + lr)*132;
        float acc = 0.f;
        #pragma unroll 8
        for (int c = 0; c < HDIM; ++c)
            acc += vr[c] * Wl[c*DOUT + jj];
        out16[(size_t)row*DOUT + jj] = acc;
    }
}

// ---------------- LDS-tiled GEMM, 64x128 tile, 4x8 acc/thread (fp32 out) ----------------
__global__ __launch_bounds__(256) void k_gemm2_64(const float* __restrict__ A, const float* __restrict__ B,
                                                  const float* __restrict__ WA, const float* __restrict__ WB,
                                                  const float* __restrict__ bias,
                                                  float* __restrict__ out, int nrows) {
    __shared__ float As[16 * 68];
    __shared__ float Bs[16 * 68];
    __shared__ float WAs[16 * 132];
    __shared__ float WBs[16 * 132];
    const int t = threadIdx.x;
    const int tx = t & 15, ty = t >> 4;
    const int row0 = blockIdx.x * 64;
    const int ar = t >> 2, ak = (t & 3) * 4;
    const int wk = t >> 4, wc = t & 15;
    float acc[4][8];
    #pragma unroll
    for (int i = 0; i < 4; ++i)
        #pragma unroll
        for (int j = 0; j < 8; ++j) acc[i][j] = 0.f;
    const bool arow_ok = (row0 + ar) < nrows;
    const float* Arow = A + (size_t)(row0 + ar) * HDIM;
    const float* Brow = B + (size_t)(row0 + ar) * HDIM;

    for (int k0 = 0; k0 < HDIM; k0 += 16) {
        float4 av = make_float4(0.f,0.f,0.f,0.f), bv = av;
        if (arow_ok) {
            av = *(const float4*)(Arow + k0 + ak);
            bv = *(const float4*)(Brow + k0 + ak);
        }
        const float4 wa0 = *(const float4*)(WA + (size_t)(k0 + wk)*HDIM + wc*4);
        const float4 wa1 = *(const float4*)(WA + (size_t)(k0 + wk)*HDIM + 64 + wc*4);
        const float4 wb0 = *(const float4*)(WB + (size_t)(k0 + wk)*HDIM + wc*4);
        const float4 wb1 = *(const float4*)(WB + (size_t)(k0 + wk)*HDIM + 64 + wc*4);
        __syncthreads();
        As[(ak+0)*68 + ar] = av.x; As[(ak+1)*68 + ar] = av.y;
        As[(ak+2)*68 + ar] = av.z; As[(ak+3)*68 + ar] = av.w;
        Bs[(ak+0)*68 + ar] = bv.x; Bs[(ak+1)*68 + ar] = bv.y;
        Bs[(ak+2)*68 + ar] = bv.z; Bs[(ak+3)*68 + ar] = bv.w;
        *(float4*)(WAs + wk*132 + wc*4) = wa0;
        *(float4*)(WAs + wk*132 + 64 + wc*4) = wa1;
        *(float4*)(WBs + wk*132 + wc*4) = wb0;
        *(float4*)(WBs + wk*132 + 64 + wc*4) = wb1;
        __syncthreads();
        #pragma unroll
        for (int k = 0; k < 16; ++k) {
            const float4 a0 = *(const float4*)(As + k*68 + ty*4);
            const float4 b0 = *(const float4*)(Bs + k*68 + ty*4);
            const float4 x0 = *(const float4*)(WAs + k*132 + tx*4);
            const float4 x1 = *(const float4*)(WAs + k*132 + 64 + tx*4);
            const float4 y0 = *(const float4*)(WBs + k*132 + tx*4);
            const float4 y1 = *(const float4*)(WBs + k*132 + 64 + tx*4);
            const float a[4]  = {a0.x,a0.y,a0.z,a0.w};
            const float b[4]  = {b0.x,b0.y,b0.z,b0.w};
            const float wa[8] = {x0.x,x0.y,x0.z,x0.w,x1.x,x1.y,x1.z,x1.w};
            const float wb[8] = {y0.x,y0.y,y0.z,y0.w,y1.x,y1.y,y1.z,y1.w};
            #pragma unroll
            for (int i = 0; i < 4; ++i)
                #pragma unroll
                for (int j = 0; j < 8; ++j)
                    acc[i][j] += a[i]*wa[j] + b[i]*wb[j];
        }
    }
    const float4 b0 = *(const float4*)(bias + tx*4);
    const float4 b1 = *(const float4*)(bias + 64 + tx*4);
    const float bj[8] = {b0.x,b0.y,b0.z,b0.w,b1.x,b1.y,b1.z,b1.w};
    #pragma unroll
    for (int i = 0; i < 4; ++i) {
        int r = row0 + ty*4 + i;
        if (r >= nrows) continue;
        float o[8];
        #pragma unroll
        for (int j = 0; j < 8; ++j) o[j] = fmaxf(acc[i][j] + bj[j], 0.f);
        *(float4*)(out + (size_t)r*HDIM + tx*4)      = make_float4(o[0],o[1],o[2],o[3]);
        *(float4*)(out + (size_t)r*HDIM + 64 + tx*4) = make_float4(o[4],o[5],o[6],o[7]);
    }
}

// single-input GEMM, bf16 output (no bias/relu): t = A @ W, [n,128] bf16
__global__ __launch_bounds__(256) void k_gemm1_64_bf(const float* __restrict__ A,
                                                     const float* __restrict__ W,
                                                     unsigned short* __restrict__ out, int nrows) {
    __shared__ float As[16 * 68];
    __shared__ float Ws[16 * 132];
    const int t = threadIdx.x;
    const int tx = t & 15, ty = t >> 4;
    const int row0 = blockIdx.x * 64;
    const int ar = t >> 2, ak = (t & 3) * 4;
    const int wk = t >> 4, wc = t & 15;
    float acc[4][8];
    #pragma unroll
    for (int i = 0; i < 4; ++i)
        #pragma unroll
        for (int j = 0; j < 8; ++j) acc[i][j] = 0.f;
    const bool arow_ok = (row0 + ar) < nrows;
    const float* Arow = A + (size_t)(row0 + ar) * HDIM;

    for (int k0 = 0; k0 < HDIM; k0 += 16) {
        float4 av = make_float4(0.f,0.f,0.f,0.f);
        if (arow_ok) av = *(const float4*)(Arow + k0 + ak);
        const float4 wv0 = *(const float4*)(W + (size_t)(k0 + wk)*HDIM + wc*4);
        const float4 wv1 = *(const float4*)(W + (size_t)(k0 + wk)*HDIM + 64 + wc*4);
        __syncthreads();
        As[(ak+0)*68 + ar] = av.x; As[(ak+1)*68 + ar] = av.y;
        As[(ak+2)*68 + ar] = av.z; As[(ak+3)*68 + ar] = av.w;
        *(float4*)(Ws + wk*132 + wc*4) = wv0;
        *(float4*)(Ws + wk*132 + 64 + wc*4) = wv1;
        __syncthreads();
        #pragma unroll
        for (int k = 0; k < 16; ++k) {
            const float4 a0 = *(const float4*)(As + k*68 + ty*4);
            const float4 w0 = *(const float4*)(Ws + k*132 + tx*4);
            const float4 w1 = *(const float4*)(Ws + k*132 + 64 + tx*4);
            const float a[4] = {a0.x,a0.y,a0.z,a0.w};
            const float w[8] = {w0.x,w0.y,w0.z,w0.w,w1.x,w1.y,w1.z,w1.w};
            #pragma unroll
            for (int i = 0; i < 4; ++i)
                #pragma unroll
                for (int j = 0; j < 8; ++j)
                    acc[i][j] += a[i]*w[j];
        }
    }
    #pragma unroll
    for (int i = 0; i < 4; ++i) {
        int r = row0 + ty*4 + i;
        if (r >= nrows) continue;
        ushort4 p0, p1;
        p0.x = f2bf(acc[i][0]); p0.y = f2bf(acc[i][1]); p0.z = f2bf(acc[i][2]); p0.w = f2bf(acc[i][3]);
        p1.x = f2bf(acc[i][4]); p1.y = f2bf(acc[i][5]); p1.z = f2bf(acc[i][6]); p1.w = f2bf(acc[i][7]);
        *(ushort4*)(out + (size_t)r*HDIM + tx*4)      = p0;
        *(ushort4*)(out + (size_t)r*HDIM + 64 + tx*4) = p1;
    }
}

// final: out[d] = mean-gather(t0 via rel0) + mean-gather(t1 via rel1) + bias
__global__ __launch_bounds__(256) void k_gather16_combine(const float* __restrict__ t0,
                                                          const float* __restrict__ t1,
                                                          const int* __restrict__ offs0,
                                                          const int* __restrict__ offs1,
                                                          const int* __restrict__ csr,
                                                          const float* __restrict__ bias,
                                                          float* __restrict__ out, int nrows) {
    int t = threadIdx.x;
    int row = blockIdx.x * 64 + (t >> 2);
    if (row >= nrows) return;
    int c = (t & 3) * 4;
    float4 acc = make_float4(0.f, 0.f, 0.f, 0.f);
    int s0 = offs0[row], s1 = offs0[row + 1];
    for (int j = s0; j < s1; ++j) {
        int s = csr[j];
        float4 v = *reinterpret_cast<const float4*>(t0 + (size_t)s*DOUT + c);
        acc.x += v.x; acc.y += v.y; acc.z += v.z; acc.w += v.w;
    }
    float sc = 1.0f / fmaxf((float)(s1 - s0), 1.0f);
    acc.x *= sc; acc.y *= sc; acc.z *= sc; acc.w *= sc;
    float4 acc2 = make_float4(0.f, 0.f, 0.f, 0.f);
    int u0 = offs1[row], u1 = offs1[row + 1];
    for (int j = u0; j < u1; ++j) {
        int s = csr[j];
        float4 v = *reinterpret_cast<const float4*>(t1 + (size_t)s*DOUT + c);
        acc2.x += v.x; acc2.y += v.y; acc2.z += v.z; acc2.w += v.w;
    }
    float sc2 = 1.0f / fmaxf((float)(u1 - u0), 1.0f);
    float4 bi = *reinterpret_cast<const float4*>(bias + c);
    acc.x += acc2.x*sc2 + bi.x; acc.y += acc2.y*sc2 + bi.y;
    acc.z += acc2.z*sc2 + bi.z; acc.w += acc2.w*sc2 + bi.w;
    *reinterpret_cast<float4*>(out + (size_t)row*DOUT + c) = acc;
}

extern "C" void kernel_launch(void* const* d_in, const int* in_sizes, int n_in,
                              void* d_out, int out_size, void* d_ws, size_t ws_size,
                              hipStream_t stream) {
    const float* feat_a = (const float*)d_in[0];
    const float* feat_b = (const float*)d_in[1];
    const float* basis0 = (const float*)d_in[3];
    const float* coef0  = (const float*)d_in[4];
    const float* bias0  = (const float*)d_in[5];
    const float* basis1 = (const float*)d_in[6];
    const float* coef1  = (const float*)d_in[7];
    const float* bias1  = (const float*)d_in[8];
    const float* basis2 = (const float*)d_in[9];
    const float* coef2  = (const float*)d_in[10];
    const float* bias2  = (const float*)d_in[11];
    const int* s0 = (const int*)d_in[12]; const int* d0 = (const int*)d_in[13];
    const int* s1 = (const int*)d_in[14]; const int* d1 = (const int*)d_in[15];
    const int* s2 = (const int*)d_in[16]; const int* d2 = (const int*)d_in[17];
    const int* s3 = (const int*)d_in[18]; const int* d3 = (const int*)d_in[19];
    const int E0 = in_sizes[12], E1 = in_sizes[14], E2 = in_sizes[16], E3 = in_sizes[18];
    const int Etot = E0 + E1 + E2 + E3;

    // ---- workspace carve-up ----
    char* base = (char*)d_ws;
    auto alloc = [&](size_t bytes) { char* p = base; base += (bytes + 255) & ~(size_t)255; return p; };
    float* W00 = (float*)alloc(HDIM*HDIM*4);
    float* W01 = (float*)alloc(HDIM*HDIM*4);
    float* W12 = (float*)alloc(HDIM*HDIM*4);
    float* W13 = (float*)alloc(HDIM*HDIM*4);
    float* W20 = (float*)alloc(HDIM*DOUT*4);
    float* W21 = (float*)alloc(HDIM*DOUT*4);
    int* offs_all = (int*)alloc((NODE_TOT + 1) * 4);
    int* csr_all  = (int*)alloc((size_t)Etot * 4);
    int* bsum     = (int*)alloc(2048 * 4);
    int* deg      = (int*)alloc(NODE_TOT * 4);
    int* bcount   = (int*)alloc(NBUCKET * 4);
    int* bofs     = (int*)alloc((NBUCKET + 1) * 4);
    int* gcur     = (int*)alloc(NBUCKET * 4);
    uint2* pairs  = (uint2*)alloc((size_t)Etot * 8);
    unsigned int* fa_bf = (unsigned int*)alloc((size_t)NA*HDIM*2);
    unsigned int* fb_bf = (unsigned int*)alloc((size_t)NB*HDIM*2);
    unsigned int* t2_bf = (unsigned int*)alloc((size_t)ND*HDIM*2);
    unsigned int* t3_bf = (unsigned int*)alloc((size_t)ND*HDIM*2);
    float* aggA = (float*)alloc((size_t)ND*HDIM*4);
    float* aggB = (float*)alloc((size_t)ND*HDIM*4);
    float* h0d  = (float*)alloc((size_t)ND*HDIM*4);
    float* t1a  = (float*)alloc((size_t)NA*DOUT*4);
    float* t1b  = (float*)alloc((size_t)NB*DOUT*4);
    float* out = (float*)d_out;

    const int* offsR[4] = {offs_all, offs_all + ND, offs_all + 2*ND, offs_all + 2*ND + NA};
    const int nbE = (Etot + EPB - 1) / EPB;

    // ---- 1. relation weights + feat bf16 conversion ----
    k_weights<<<(HDIM*HDIM+255)/256, 256, 0, stream>>>(basis0, coef0, W00, W01, 0, 1, HDIM*HDIM);
    k_weights<<<(HDIM*HDIM+255)/256, 256, 0, stream>>>(basis1, coef1, W12, W13, 2, 3, HDIM*HDIM);
    k_weights<<<(HDIM*DOUT+255)/256, 256, 0, stream>>>(basis2, coef2, W20, W21, 0, 1, HDIM*DOUT);
    k_cvt_bf16<<<(NA*16+255)/256, 256, 0, stream>>>(feat_a, fa_bf, NA*16);
    k_cvt_bf16<<<(NB*16+255)/256, 256, 0, stream>>>(feat_b, fb_bf, NB*16);

    // ---- 2. bucketed CSR build ----
    {
        hipMemsetAsync(bcount, 0, NBUCKET * 4, stream);
        k_bhist<<<nbE, 256, 0, stream>>>(s0,d0,s1,d1,s2,d2,s3,d3, E0,E1,E2, Etot, bcount);
        k_bscan<<<1, 1024, 0, stream>>>(bcount, bofs, gcur);
        k_bscatter<<<nbE, 256, 0, stream>>>(s0,d0,s1,d1,s2,d2,s3,d3, E0,E1,E2, Etot, gcur, pairs);
        k_bdeg<<<NBUCKET, 256, 0, stream>>>(pairs, bofs, deg);
        int nb = (NODE_TOT + 1023) / 1024;
        k_scan1<<<nb, 1024, 0, stream>>>(deg, offs_all, bsum, NODE_TOT);
        k_scan2<<<1, 1024, 0, stream>>>(bsum, nb);
        k_scan3<<<nb, 1024, 0, stream>>>(offs_all, bsum, NODE_TOT);
        k_bfill<<<NBUCKET, 256, 0, stream>>>(pairs, bofs, offs_all, csr_all);
    }

    // ---- 3. layer 0: h0d = relu(mean_e0(feat_a) @ W00 + mean_e1(feat_b) @ W01 + bias0) ----
    k_gather128_bf<<<(ND+3)/4, 256, 0, stream>>>(fa_bf, offsR[0], csr_all, aggA, ND);
    k_gather128_bf<<<(ND+3)/4, 256, 0, stream>>>(fb_bf, offsR[1], csr_all, aggB, ND);
    k_gemm2_64<<<(ND+63)/64, 256, 0, stream>>>(aggA, aggB, W00, W01, bias0, h0d, ND);

    // ---- 4. layer 1 transform (50k rows, bf16 out) ----
    k_gemm1_64_bf<<<(ND+63)/64, 256, 0, stream>>>(h0d, W12, (unsigned short*)t2_bf, ND);
    k_gemm1_64_bf<<<(ND+63)/64, 256, 0, stream>>>(h0d, W13, (unsigned short*)t3_bf, ND);

    // ---- 5. fused layer-1 aggregate + bias/relu + layer-2 transform -> t1a/t1b ----
    k_gather_trans16<<<(NA+15)/16, 256, 0, stream>>>(t2_bf, offsR[2], csr_all, bias1, W20, t1a, NA);
    k_gather_trans16<<<(NB+15)/16, 256, 0, stream>>>(t3_bf, offsR[3], csr_all, bias1, W21, t1b, NB);

    // ---- 6. final combine ----
    k_gather16_combine<<<(ND+63)/64, 256, 0, stream>>>(t1a, t1b, offsR[0], offsR[1], csr_all,
                                                       bias2, out, ND);
}

// Round 8
// 394.233 us; speedup vs baseline: 5.4535x; 1.3043x over previous
//
#include <hip/hip_runtime.h>

#define NA 100000
#define NB 100000
#define ND 50000
#define HDIM 128
#define DOUT 16
// concatenated dst-node space: rel0 d:[0,ND) rel1 d:[ND,2ND) rel2 a:[2ND,2ND+NA) rel3 b:[2ND+NA,...)
#define NODE_TOT (2*ND + NA + NB)
#define BSH 9
#define BKN 512
#define NBUCKET ((NODE_TOT + BKN - 1) >> BSH)   // 586
#define EPB 4096                                 // edges per block, bucket passes

typedef __attribute__((ext_vector_type(8))) short short8v;   // 8 bf16 (4 VGPRs)
typedef __attribute__((ext_vector_type(4))) float f32x4;

__device__ __forceinline__ unsigned short f2bf(float f) {
    unsigned u = __float_as_uint(f);
    return (unsigned short)((u + 0x7fffu + ((u >> 16) & 1u)) >> 16);
}

struct EdgeT { int node; int src; };
__device__ __forceinline__ EdgeT edge_at(int g,
    const int* __restrict__ s0, const int* __restrict__ d0,
    const int* __restrict__ s1, const int* __restrict__ d1,
    const int* __restrict__ s2, const int* __restrict__ d2,
    const int* __restrict__ s3, const int* __restrict__ d3,
    int E0, int E1, int E2) {
    EdgeT e;
    if (g < E0)             { e.node = d0[g];                    e.src = s0[g]; }
    else if (g < E0+E1)     { e.node = ND + d1[g-E0];            e.src = s1[g-E0]; }
    else if (g < E0+E1+E2)  { e.node = 2*ND + d2[g-E0-E1];       e.src = s2[g-E0-E1]; }
    else                    { e.node = 2*ND+NA + d3[g-E0-E1-E2]; e.src = s3[g-E0-E1-E2]; }
    return e;
}

// ---------------- weights (f32, for the 128->16 path) ----------------
__global__ __launch_bounds__(256) void k_weights(const float* __restrict__ basis,
                                                 const float* __restrict__ coef,
                                                 float* __restrict__ W0, float* __restrict__ W1,
                                                 int r0, int r1, int n) {
    int i = blockIdx.x * 256 + threadIdx.x;
    if (i >= n) return;
    float b0 = basis[i], b1 = basis[n + i];
    W0[i] = coef[r0*2+0]*b0 + coef[r0*2+1]*b1;
    W1[i] = coef[r1*2+0]*b0 + coef[r1*2+1]*b1;
}

// bf16 TRANSPOSED weights for MFMA B-operand: WT[n][k] = W[k][n], 128x128
__global__ __launch_bounds__(256) void k_weights_bfT(const float* __restrict__ basis,
                                                     const float* __restrict__ coef,
                                                     unsigned short* __restrict__ WT0,
                                                     unsigned short* __restrict__ WT1,
                                                     int r0, int r1) {
    int i = blockIdx.x * 256 + threadIdx.x;   // i = k*128 + j
    if (i >= HDIM*HDIM) return;
    int k = i >> 7, j = i & 127;
    float b0 = basis[i], b1 = basis[HDIM*HDIM + i];
    WT0[(size_t)j*HDIM + k] = f2bf(coef[r0*2+0]*b0 + coef[r0*2+1]*b1);
    WT1[(size_t)j*HDIM + k] = f2bf(coef[r1*2+0]*b0 + coef[r1*2+1]*b1);
}

// ---------------- fp32 -> bf16 conversion (8 elems/thread) ----------------
__global__ __launch_bounds__(256) void k_cvt_bf16(const float* __restrict__ in,
                                                  unsigned int* __restrict__ out, int n8) {
    int i = blockIdx.x * 256 + threadIdx.x;
    if (i >= n8) return;
    const float4 a = *(const float4*)(in + (size_t)i*8);
    const float4 b = *(const float4*)(in + (size_t)i*8 + 4);
    uint4 p;
    p.x = (unsigned)f2bf(a.x) | ((unsigned)f2bf(a.y) << 16);
    p.y = (unsigned)f2bf(a.z) | ((unsigned)f2bf(a.w) << 16);
    p.z = (unsigned)f2bf(b.x) | ((unsigned)f2bf(b.y) << 16);
    p.w = (unsigned)f2bf(b.z) | ((unsigned)f2bf(b.w) << 16);
    *(uint4*)(out + (size_t)i*4) = p;
}

// ---------------- bucketed CSR build ----------------
__global__ __launch_bounds__(256) void k_bhist(const int* __restrict__ s0, const int* __restrict__ d0,
                                               const int* __restrict__ s1, const int* __restrict__ d1,
                                               const int* __restrict__ s2, const int* __restrict__ d2,
                                               const int* __restrict__ s3, const int* __restrict__ d3,
                                               int E0, int E1, int E2, int Etot,
                                               int* __restrict__ bcount) {
    __shared__ int h[NBUCKET];
    for (int i = threadIdx.x; i < NBUCKET; i += 256) h[i] = 0;
    __syncthreads();
    int g0 = blockIdx.x * EPB + threadIdx.x;
    #pragma unroll
    for (int i = 0; i < EPB/256; ++i) {
        int g = g0 + i*256;
        if (g < Etot) {
            EdgeT e = edge_at(g, s0,d0,s1,d1,s2,d2,s3,d3, E0,E1,E2);
            atomicAdd(&h[e.node >> BSH], 1);
        }
    }
    __syncthreads();
    for (int i = threadIdx.x; i < NBUCKET; i += 256)
        if (h[i]) atomicAdd(&bcount[i], h[i]);
}

__global__ __launch_bounds__(1024) void k_bscan(const int* __restrict__ bcount,
                                                int* __restrict__ bofs,
                                                int* __restrict__ gcur) {
    __shared__ int sh[1024];
    int t = threadIdx.x;
    sh[t] = (t < NBUCKET) ? bcount[t] : 0;
    __syncthreads();
    for (int off = 1; off < 1024; off <<= 1) {
        int v = (t >= off) ? sh[t - off] : 0;
        __syncthreads();
        sh[t] += v;
        __syncthreads();
    }
    if (t < NBUCKET) {
        bofs[t + 1] = sh[t];
        gcur[t] = sh[t] - bcount[t];
        if (t == 0) bofs[0] = 0;
    }
}

__global__ __launch_bounds__(256) void k_bscatter(const int* __restrict__ s0, const int* __restrict__ d0,
                                                  const int* __restrict__ s1, const int* __restrict__ d1,
                                                  const int* __restrict__ s2, const int* __restrict__ d2,
                                                  const int* __restrict__ s3, const int* __restrict__ d3,
                                                  int E0, int E1, int E2, int Etot,
                                                  int* __restrict__ gcur,
                                                  uint2* __restrict__ pairs) {
    __shared__ int hist[NBUCKET];
    __shared__ int base[NBUCKET];
    for (int i = threadIdx.x; i < NBUCKET; i += 256) hist[i] = 0;
    __syncthreads();
    int g0 = blockIdx.x * EPB + threadIdx.x;
    int nd[EPB/256], sr[EPB/256], rk[EPB/256];
    #pragma unroll
    for (int i = 0; i < EPB/256; ++i) {
        int g = g0 + i*256;
        if (g < Etot) {
            EdgeT e = edge_at(g, s0,d0,s1,d1,s2,d2,s3,d3, E0,E1,E2);
            nd[i] = e.node; sr[i] = e.src;
            rk[i] = atomicAdd(&hist[e.node >> BSH], 1);
        } else nd[i] = -1;
    }
    __syncthreads();
    for (int i = threadIdx.x; i < NBUCKET; i += 256)
        if (hist[i]) base[i] = atomicAdd(&gcur[i], hist[i]);
    __syncthreads();
    #pragma unroll
    for (int i = 0; i < EPB/256; ++i) {
        if (nd[i] >= 0) {
            uint2 p; p.x = (unsigned)nd[i]; p.y = (unsigned)sr[i];
            pairs[base[nd[i] >> BSH] + rk[i]] = p;
        }
    }
}

__global__ __launch_bounds__(256) void k_bdeg(const uint2* __restrict__ pairs,
                                              const int* __restrict__ bofs,
                                              int* __restrict__ deg) {
    __shared__ int ld[BKN];
    int b = blockIdx.x;
    for (int i = threadIdx.x; i < BKN; i += 256) ld[i] = 0;
    __syncthreads();
    int j0 = bofs[b], j1 = bofs[b + 1];
    int nbase = b << BSH;
    for (int j = j0 + threadIdx.x; j < j1; j += 256)
        atomicAdd(&ld[pairs[j].x - nbase], 1);
    __syncthreads();
    for (int i = threadIdx.x; i < BKN && nbase + i < NODE_TOT; i += 256)
        deg[nbase + i] = ld[i];
}

__global__ __launch_bounds__(256) void k_bfill(const uint2* __restrict__ pairs,
                                               const int* __restrict__ bofs,
                                               const int* __restrict__ offs,
                                               int* __restrict__ csr) {
    __shared__ int cur[BKN];
    int b = blockIdx.x;
    int nbase = b << BSH;
    for (int i = threadIdx.x; i < BKN && nbase + i < NODE_TOT; i += 256)
        cur[i] = offs[nbase + i];
    __syncthreads();
    int j0 = bofs[b], j1 = bofs[b + 1];
    for (int j = j0 + threadIdx.x; j < j1; j += 256) {
        uint2 e = pairs[j];
        int p = atomicAdd(&cur[e.x - nbase], 1);
        csr[p] = (int)e.y;
    }
}

// ---------------- global scans over NODE_TOT (deg -> offs) ----------------
__global__ __launch_bounds__(1024) void k_scan1(const int* __restrict__ deg,
                                                int* __restrict__ offs,
                                                int* __restrict__ bsum, int N) {
    __shared__ int sh[1024];
    int i = blockIdx.x * 1024 + threadIdx.x;
    int v = (i < N) ? deg[i] : 0;
    sh[threadIdx.x] = v;
    __syncthreads();
    for (int off = 1; off < 1024; off <<= 1) {
        int t = (threadIdx.x >= off) ? sh[threadIdx.x - off] : 0;
        __syncthreads();
        sh[threadIdx.x] += t;
        __syncthreads();
    }
    if (i < N) offs[i + 1] = sh[threadIdx.x];
    if (threadIdx.x == 1023) bsum[blockIdx.x] = sh[1023];
    if (i == 0) offs[0] = 0;
}

__global__ __launch_bounds__(1024) void k_scan2(int* __restrict__ bsum, int nb) {
    __shared__ int sh[1024];
    int t = threadIdx.x;
    sh[t] = (t < nb) ? bsum[t] : 0;
    __syncthreads();
    for (int off = 1; off < 1024; off <<= 1) {
        int v = (t >= off) ? sh[t - off] : 0;
        __syncthreads();
        sh[t] += v;
        __syncthreads();
    }
    if (t < nb) bsum[t] = sh[t];
}

__global__ __launch_bounds__(1024) void k_scan3(int* __restrict__ offs,
                                                const int* __restrict__ bsum, int N) {
    int i = blockIdx.x * 1024 + threadIdx.x;
    if (blockIdx.x > 0 && i < N) offs[i + 1] += bsum[blockIdx.x - 1];
}

// ---------------- gather (bf16 table -> bf16 out, CSR, mean) ----------------
__global__ __launch_bounds__(256) void k_gather128_bf(const unsigned int* __restrict__ tbl,
                                                      const int* __restrict__ offs,
                                                      const int* __restrict__ csr,
                                                      unsigned int* __restrict__ outbf, int nrows) {
    int w = threadIdx.x >> 6;
    int lane = threadIdx.x & 63;
    int row = blockIdx.x * 4 + w;
    if (row >= nrows) return;
    int s0 = offs[row], s1 = offs[row + 1];
    float ax = 0.f, ay = 0.f;
    int j = s0;
    for (; j + 1 < s1; j += 2) {
        unsigned u1 = tbl[(size_t)csr[j]*64 + lane];
        unsigned u2 = tbl[(size_t)csr[j+1]*64 + lane];
        ax += __uint_as_float(u1 << 16) + __uint_as_float(u2 << 16);
        ay += __uint_as_float(u1 & 0xffff0000u) + __uint_as_float(u2 & 0xffff0000u);
    }
    if (j < s1) {
        unsigned u1 = tbl[(size_t)csr[j]*64 + lane];
        ax += __uint_as_float(u1 << 16);
        ay += __uint_as_float(u1 & 0xffff0000u);
    }
    float sc = 1.0f / fmaxf((float)(s1 - s0), 1.0f);
    outbf[(size_t)row*64 + lane] =
        (unsigned)f2bf(ax*sc) | ((unsigned)f2bf(ay*sc) << 16);
}

// ---------------- MFMA GEMM: out_bf16[n,128] = [relu]( A0@W0 (+A1@W1) + bias ) ----------------
// A bf16 [n][128]; WT bf16 [128][128] TRANSPOSED (WT[n][k]); 64 rows x 128 cols per block.
// 4 waves; wave w owns cols [w*32, w*32+32). Fragments per verified m89 layout.
__global__ __launch_bounds__(256) void k_mfma_gemm(const unsigned short* __restrict__ A0,
                                                   const unsigned short* __restrict__ A1,
                                                   const unsigned short* __restrict__ WT0,
                                                   const unsigned short* __restrict__ WT1,
                                                   const float* __restrict__ bias, int relu,
                                                   unsigned short* __restrict__ outbf, int nrows) {
    const int l = threadIdx.x & 63;
    const int w = threadIdx.x >> 6;
    const int row0 = blockIdx.x * 64;
    const int colw = w * 32;
    const int kl = (l >> 4) * 8;
    const int rl = l & 15;

    f32x4 acc[4][2];
    #pragma unroll
    for (int r = 0; r < 4; ++r) { acc[r][0] = (f32x4)0.f; acc[r][1] = (f32x4)0.f; }
    const short8v az = {0,0,0,0,0,0,0,0};

    #pragma unroll
    for (int s = 0; s < 4; ++s) {
        const int k0 = s * 32;
        short8v b0 = *(const short8v*)(WT0 + (size_t)(colw + rl)*HDIM + k0 + kl);
        short8v b1 = *(const short8v*)(WT0 + (size_t)(colw + 16 + rl)*HDIM + k0 + kl);
        short8v a[4];
        #pragma unroll
        for (int r = 0; r < 4; ++r) {
            int row = row0 + r*16 + rl;
            a[r] = (row < nrows) ? *(const short8v*)(A0 + (size_t)row*HDIM + k0 + kl) : az;
        }
        #pragma unroll
        for (int r = 0; r < 4; ++r) {
            acc[r][0] = __builtin_amdgcn_mfma_f32_16x16x32_bf16(a[r], b0, acc[r][0], 0, 0, 0);
            acc[r][1] = __builtin_amdgcn_mfma_f32_16x16x32_bf16(a[r], b1, acc[r][1], 0, 0, 0);
        }
    }
    if (A1) {
        #pragma unroll
        for (int s = 0; s < 4; ++s) {
            const int k0 = s * 32;
            short8v b0 = *(const short8v*)(WT1 + (size_t)(colw + rl)*HDIM + k0 + kl);
            short8v b1 = *(const short8v*)(WT1 + (size_t)(colw + 16 + rl)*HDIM + k0 + kl);
            short8v a[4];
            #pragma unroll
            for (int r = 0; r < 4; ++r) {
                int row = row0 + r*16 + rl;
                a[r] = (row < nrows) ? *(const short8v*)(A1 + (size_t)row*HDIM + k0 + kl) : az;
            }
            #pragma unroll
            for (int r = 0; r < 4; ++r) {
                acc[r][0] = __builtin_amdgcn_mfma_f32_16x16x32_bf16(a[r], b0, acc[r][0], 0, 0, 0);
                acc[r][1] = __builtin_amdgcn_mfma_f32_16x16x32_bf16(a[r], b1, acc[r][1], 0, 0, 0);
            }
        }
    }
    // epilogue: D col = colw + c*16 + (l&15); row = row0 + r*16 + (l>>4)*4 + j
    const float bc0 = bias ? bias[colw + rl] : 0.f;
    const float bc1 = bias ? bias[colw + 16 + rl] : 0.f;
    #pragma unroll
    for (int r = 0; r < 4; ++r) {
        #pragma unroll
        for (int j = 0; j < 4; ++j) {
            int row = row0 + r*16 + (l >> 4)*4 + j;
            if (row < nrows) {
                float v0 = acc[r][0][j] + bc0;
                float v1 = acc[r][1][j] + bc1;
                if (relu) { v0 = fmaxf(v0, 0.f); v1 = fmaxf(v1, 0.f); }
                outbf[(size_t)row*HDIM + colw + rl]      = f2bf(v0);
                outbf[(size_t)row*HDIM + colw + 16 + rl] = f2bf(v1);
            }
        }
    }
}

// ---------------- fused layer-1 gather + bias + relu + 128->16 transform ----------------
__global__ __launch_bounds__(256) void k_gather_trans16(const unsigned int* __restrict__ tbl,
                                                        const int* __restrict__ offs,
                                                        const int* __restrict__ csr,
                                                        const float* __restrict__ bias,
                                                        const float* __restrict__ W,
                                                        float* __restrict__ out16, int nrows) {
    __shared__ float Wl[HDIM * DOUT];
    __shared__ float vbuf[16 * 132];
    const int t = threadIdx.x;
    *(float4*)(Wl + t*8)     = *(const float4*)(W + t*8);
    *(float4*)(Wl + t*8 + 4) = *(const float4*)(W + t*8 + 4);
    __syncthreads();
    const int w = t >> 6, lane = t & 63;
    const float b0 = bias[2*lane], b1 = bias[2*lane + 1];
    const int rbase = blockIdx.x * 16 + w * 4;
    #pragma unroll
    for (int r = 0; r < 4; ++r) {
        int row = rbase + r;
        if (row < nrows) {
            int s0 = offs[row], s1 = offs[row + 1];
            float ax = 0.f, ay = 0.f;
            int j = s0;
            for (; j + 1 < s1; j += 2) {
                unsigned u1 = tbl[(size_t)csr[j]*64 + lane];
                unsigned u2 = tbl[(size_t)csr[j+1]*64 + lane];
                ax += __uint_as_float(u1 << 16) + __uint_as_float(u2 << 16);
                ay += __uint_as_float(u1 & 0xffff0000u) + __uint_as_float(u2 & 0xffff0000u);
            }
            if (j < s1) {
                unsigned u1 = tbl[(size_t)csr[j]*64 + lane];
                ax += __uint_as_float(u1 << 16);
                ay += __uint_as_float(u1 & 0xffff0000u);
            }
            float sc = 1.0f / fmaxf((float)(s1 - s0), 1.0f);
            float v0 = fmaxf(ax*sc + b0, 0.f);
            float v1 = fmaxf(ay*sc + b1, 0.f);
            *(float2*)(vbuf + (w*4 + r)*132 + 2*lane) = make_float2(v0, v1);
        }
    }
    __syncthreads();
    const int lr = lane >> 4, jj = lane & 15;
    int row = rbase + lr;
    if (row < nrows) {
        const float* vr = vbuf + (w*4 + lr)*132;
        float acc = 0.f;
        #pragma unroll 8
        for (int c = 0; c < HDIM; ++c)
            acc += vr[c] * Wl[c*DOUT + jj];
        out16[(size_t)row*DOUT + jj] = acc;
    }
}

// final: out[d] = mean-gather(t0 via rel0) + mean-gather(t1 via rel1) + bias
__global__ __launch_bounds__(256) void k_gather16_combine(const float* __restrict__ t0,
                                                          const float* __restrict__ t1,
                                                          const int* __restrict__ offs0,
                                                          const int* __restrict__ offs1,
                                                          const int* __restrict__ csr,
                                                          const float* __restrict__ bias,
                                                          float* __restrict__ out, int nrows) {
    int t = threadIdx.x;
    int row = blockIdx.x * 64 + (t >> 2);
    if (row >= nrows) return;
    int c = (t & 3) * 4;
    float4 acc = make_float4(0.f, 0.f, 0.f, 0.f);
    int s0 = offs0[row], s1 = offs0[row + 1];
    for (int j = s0; j < s1; ++j) {
        int s = csr[j];
        float4 v = *reinterpret_cast<const float4*>(t0 + (size_t)s*DOUT + c);
        acc.x += v.x; acc.y += v.y; acc.z += v.z; acc.w += v.w;
    }
    float sc = 1.0f / fmaxf((float)(s1 - s0), 1.0f);
    acc.x *= sc; acc.y *= sc; acc.z *= sc; acc.w *= sc;
    float4 acc2 = make_float4(0.f, 0.f, 0.f, 0.f);
    int u0 = offs1[row], u1 = offs1[row + 1];
    for (int j = u0; j < u1; ++j) {
        int s = csr[j];
        float4 v = *reinterpret_cast<const float4*>(t1 + (size_t)s*DOUT + c);
        acc2.x += v.x; acc2.y += v.y; acc2.z += v.z; acc2.w += v.w;
    }
    float sc2 = 1.0f / fmaxf((float)(u1 - u0), 1.0f);
    float4 bi = *reinterpret_cast<const float4*>(bias + c);
    acc.x += acc2.x*sc2 + bi.x; acc.y += acc2.y*sc2 + bi.y;
    acc.z += acc2.z*sc2 + bi.z; acc.w += acc2.w*sc2 + bi.w;
    *reinterpret_cast<float4*>(out + (size_t)row*DOUT + c) = acc;
}

extern "C" void kernel_launch(void* const* d_in, const int* in_sizes, int n_in,
                              void* d_out, int out_size, void* d_ws, size_t ws_size,
                              hipStream_t stream) {
    const float* feat_a = (const float*)d_in[0];
    const float* feat_b = (const float*)d_in[1];
    const float* basis0 = (const float*)d_in[3];
    const float* coef0  = (const float*)d_in[4];
    const float* bias0  = (const float*)d_in[5];
    const float* basis1 = (const float*)d_in[6];
    const float* coef1  = (const float*)d_in[7];
    const float* bias1  = (const float*)d_in[8];
    const float* basis2 = (const float*)d_in[9];
    const float* coef2  = (const float*)d_in[10];
    const float* bias2  = (const float*)d_in[11];
    const int* s0 = (const int*)d_in[12]; const int* d0 = (const int*)d_in[13];
    const int* s1 = (const int*)d_in[14]; const int* d1 = (const int*)d_in[15];
    const int* s2 = (const int*)d_in[16]; const int* d2 = (const int*)d_in[17];
    const int* s3 = (const int*)d_in[18]; const int* d3 = (const int*)d_in[19];
    const int E0 = in_sizes[12], E1 = in_sizes[14], E2 = in_sizes[16], E3 = in_sizes[18];
    const int Etot = E0 + E1 + E2 + E3;

    // ---- workspace carve-up ----
    char* base = (char*)d_ws;
    auto alloc = [&](size_t bytes) { char* p = base; base += (bytes + 255) & ~(size_t)255; return p; };
    unsigned short* WT00 = (unsigned short*)alloc(HDIM*HDIM*2);
    unsigned short* WT01 = (unsigned short*)alloc(HDIM*HDIM*2);
    unsigned short* WT12 = (unsigned short*)alloc(HDIM*HDIM*2);
    unsigned short* WT13 = (unsigned short*)alloc(HDIM*HDIM*2);
    float* W20 = (float*)alloc(HDIM*DOUT*4);
    float* W21 = (float*)alloc(HDIM*DOUT*4);
    int* offs_all = (int*)alloc((NODE_TOT + 1) * 4);
    int* csr_all  = (int*)alloc((size_t)Etot * 4);
    int* bsum     = (int*)alloc(2048 * 4);
    int* deg      = (int*)alloc(NODE_TOT * 4);
    int* bcount   = (int*)alloc(NBUCKET * 4);
    int* bofs     = (int*)alloc((NBUCKET + 1) * 4);
    int* gcur     = (int*)alloc(NBUCKET * 4);
    uint2* pairs  = (uint2*)alloc((size_t)Etot * 8);
    unsigned int* fa_bf  = (unsigned int*)alloc((size_t)NA*HDIM*2);
    unsigned int* fb_bf  = (unsigned int*)alloc((size_t)NB*HDIM*2);
    unsigned int* aggA_bf = (unsigned int*)alloc((size_t)ND*HDIM*2);
    unsigned int* aggB_bf = (unsigned int*)alloc((size_t)ND*HDIM*2);
    unsigned short* h0_bf = (unsigned short*)alloc((size_t)ND*HDIM*2);
    unsigned int* t2_bf  = (unsigned int*)alloc((size_t)ND*HDIM*2);
    unsigned int* t3_bf  = (unsigned int*)alloc((size_t)ND*HDIM*2);
    float* t1a  = (float*)alloc((size_t)NA*DOUT*4);
    float* t1b  = (float*)alloc((size_t)NB*DOUT*4);
    float* out = (float*)d_out;

    const int* offsR[4] = {offs_all, offs_all + ND, offs_all + 2*ND, offs_all + 2*ND + NA};
    const int nbE = (Etot + EPB - 1) / EPB;

    // ---- 1. relation weights (bf16-transposed for MFMA) + feat bf16 conversion ----
    k_weights_bfT<<<(HDIM*HDIM+255)/256, 256, 0, stream>>>(basis0, coef0, WT00, WT01, 0, 1);
    k_weights_bfT<<<(HDIM*HDIM+255)/256, 256, 0, stream>>>(basis1, coef1, WT12, WT13, 2, 3);
    k_weights<<<(HDIM*DOUT+255)/256, 256, 0, stream>>>(basis2, coef2, W20, W21, 0, 1, HDIM*DOUT);
    k_cvt_bf16<<<(NA*16+255)/256, 256, 0, stream>>>(feat_a, fa_bf, NA*16);
    k_cvt_bf16<<<(NB*16+255)/256, 256, 0, stream>>>(feat_b, fb_bf, NB*16);

    // ---- 2. bucketed CSR build ----
    {
        hipMemsetAsync(bcount, 0, NBUCKET * 4, stream);
        k_bhist<<<nbE, 256, 0, stream>>>(s0,d0,s1,d1,s2,d2,s3,d3, E0,E1,E2, Etot, bcount);
        k_bscan<<<1, 1024, 0, stream>>>(bcount, bofs, gcur);
        k_bscatter<<<nbE, 256, 0, stream>>>(s0,d0,s1,d1,s2,d2,s3,d3, E0,E1,E2, Etot, gcur, pairs);
        k_bdeg<<<NBUCKET, 256, 0, stream>>>(pairs, bofs, deg);
        int nb = (NODE_TOT + 1023) / 1024;
        k_scan1<<<nb, 1024, 0, stream>>>(deg, offs_all, bsum, NODE_TOT);
        k_scan2<<<1, 1024, 0, stream>>>(bsum, nb);
        k_scan3<<<nb, 1024, 0, stream>>>(offs_all, bsum, NODE_TOT);
        k_bfill<<<NBUCKET, 256, 0, stream>>>(pairs, bofs, offs_all, csr_all);
    }

    // ---- 3. layer 0: gathers (bf16 out) + MFMA gemm2 -> h0 (bf16) ----
    k_gather128_bf<<<(ND+3)/4, 256, 0, stream>>>(fa_bf, offsR[0], csr_all, aggA_bf, ND);
    k_gather128_bf<<<(ND+3)/4, 256, 0, stream>>>(fb_bf, offsR[1], csr_all, aggB_bf, ND);
    k_mfma_gemm<<<(ND+63)/64, 256, 0, stream>>>((const unsigned short*)aggA_bf,
                                                (const unsigned short*)aggB_bf,
                                                WT00, WT01, bias0, 1, h0_bf, ND);

    // ---- 4. layer 1 transform (50k rows, bf16 out) via MFMA ----
    k_mfma_gemm<<<(ND+63)/64, 256, 0, stream>>>(h0_bf, nullptr, WT12, nullptr, nullptr, 0,
                                                (unsigned short*)t2_bf, ND);
    k_mfma_gemm<<<(ND+63)/64, 256, 0, stream>>>(h0_bf, nullptr, WT13, nullptr, nullptr, 0,
                                                (unsigned short*)t3_bf, ND);

    // ---- 5. fused layer-1 aggregate + bias/relu + layer-2 transform -> t1a/t1b ----
    k_gather_trans16<<<(NA+15)/16, 256, 0, stream>>>(t2_bf, offsR[2], csr_all, bias1, W20, t1a, NA);
    k_gather_trans16<<<(NB+15)/16, 256, 0, stream>>>(t3_bf, offsR[3], csr_all, bias1, W21, t1b, NB);

    // ---- 6. final combine ----
    k_gather16_combine<<<(ND+63)/64, 256, 0, stream>>>(t1a, t1b, offsR[0], offsR[1], csr_all,
                                                       bias2, out, ND);
}